// Round 6
// baseline (1245.497 us; speedup 1.0000x reference)
//
#include <hip/hip_runtime.h>

typedef unsigned short u16;
typedef unsigned int u32;
typedef unsigned long long u64;

#define N_USERS 100000
#define N_ITEMS 200000
#define N_NODES 300000
#define D 64
#define HYP 128
#define NNZ 4000000

// out is 96M fp32 elems: [user_out|item_out|gcn_hidden(2)|hgnn_hidden(2)]
constexpr long long SZL      = 19200000LL;        // one 300000x64 tensor
constexpr long long OUT_GCN0 = SZL;               // gcn_hidden base
constexpr long long OUT_HG0  = 3*SZL;             // hgnn_hidden base
// CSR {col,val} pairs overlaid on hgnn[l=1] region [4*SZL,5*SZL): written only
// by the final fused GEMM (after the last SpMM read of the pairs).
constexpr long long OUT_PAIR = 4*SZL;
// step3 partial tiles (587 x 8192 floats = 19.2MB) right after pair_s in the
// same hgnn[l=1] region; consumed by k_reduce before gemm1 overwrites hg[1].
constexpr long long OUT_PART = OUT_PAIR + 8000000LL;
// rank_e (NNZ ints, 16MB) overlaid on gcn_hidden[l=1] region [2*SZL,3*SZL):
// consumed by k_f2's place path, long before layer-1 writes gcn[1].
constexpr long long OUT_RANK = 2*SZL;

#define S3_CHUNK 512
constexpr int NB_S3U = (N_USERS + S3_CHUNK - 1)/S3_CHUNK;  // 196
constexpr int NB_S3I = (N_ITEMS + S3_CHUNK - 1)/S3_CHUNK;  // 391
constexpr int NB_S3  = NB_S3U + NB_S3I;                    // 587
constexpr int UB64   = N_USERS/32;                         // 3125 user gemm blocks
constexpr int NB_GEMM= N_NODES/32;                         // 9375
constexpr int NB_INIT= 9375;                               // init blocks
constexpr int NB_E4  = (NNZ/4 + 255)/256;                  // 3907 (rank/place blocks)
constexpr int NB_SPMM= N_NODES/4;                          // 75000
constexpr int RG_U   = (NB_S3U + 31)/32;                   // 7 reduce groups (user)
constexpr int RG_I   = (NB_S3I + 31)/32;                   // 13 reduce groups (item)

typedef __attribute__((ext_vector_type(8))) short short8;
typedef __attribute__((ext_vector_type(4))) float f32x4;

__device__ __forceinline__ float bf2f(u16 u){ u32 i = ((u32)u) << 16; return __builtin_bit_cast(float, i); }
__device__ __forceinline__ u16 f2bf(float f){
  u32 i = __builtin_bit_cast(u32, f);
  return (u16)((i + 0x7FFFu + ((i >> 16) & 1u)) >> 16);
}

// ---------------- init body: emb (fp32) -> h_bf (bf16), hsum (fp32) ----------
__device__ __forceinline__ void init_body(int t, const float* __restrict__ ue,
                                          const float* __restrict__ ie,
                                          u16* __restrict__ h_bf, float* __restrict__ hsum){
  int base = t*8;
  const float* src = (base < N_USERS*D) ? (ue + base) : (ie + (base - N_USERS*D));
  float4 v0 = *(const float4*)(src);
  float4 v1 = *(const float4*)(src + 4);
  *(float4*)(hsum + base)     = v0;
  *(float4*)(hsum + base + 4) = v1;
  uint4 p;
  p.x = (u32)f2bf(v0.x) | ((u32)f2bf(v0.y)<<16);
  p.y = (u32)f2bf(v0.z) | ((u32)f2bf(v0.w)<<16);
  p.z = (u32)f2bf(v1.x) | ((u32)f2bf(v1.y)<<16);
  p.w = (u32)f2bf(v1.z) | ((u32)f2bf(v1.w)<<16);
  *(uint4*)(h_bf + base) = p;
}

// ---------------- GEMM body ---------------------------------------------------
// C[M x N] = A[M x K] @ B[K x N]; A row-major bf16 (AF32=false) or fp32
// converted on the fly with the same f2bf rounding (AF32=true -> bit-identical
// to converting first). B fp32 staged in LDS as bf16. 32 rows/block, 4 waves.
// User+item merged: blocks [0,ublocks) = user, rest = item.
// FUSE: layer epilogue h = gcn+hg; hsum += h; hbf = bf16(h); hg stored
// nontemporally (streaming, no reuse).
template<int K, int N, bool C32, bool FUSE, bool AF32>
__device__ __forceinline__ void gemm_body(int bid, const void* __restrict__ A0,
                                          const float* __restrict__ Bu,
                                          const float* __restrict__ Bi,
                                          void* __restrict__ Cv,
                                          const float* __restrict__ gcn0,
                                          float* __restrict__ hsum0,
                                          u16* __restrict__ hbf0,
                                          int ublocks, u32* blds){
  bool it = bid >= ublocks;
  int blk = it ? bid - ublocks : bid;
  const float* B = it ? Bi : Bu;
  size_t aoff = it ? (size_t)ublocks*32*K : 0;
  size_t co   = it ? (size_t)ublocks*32*N : 0;   // C/gcn/hsum/hbf element offset

  constexpr int SROW = N + 2;                 // padded u16 stride (odd dword stride)
  constexpr int PAIRS = K*N/2;
  for (int p = threadIdx.x; p < PAIRS; p += 256){
    int k = p/(N/2), c2 = p%(N/2);
    float f0 = B[2*p], f1 = B[2*p+1];
    blds[k*(SROW/2) + c2] = (u32)f2bf(f0) | ((u32)f2bf(f1)<<16);
  }
  __syncthreads();
  const u16* bl = (const u16*)blds;
  int wave = threadIdx.x>>6, lane = threadIdx.x&63, q = lane>>4, lm = lane&15;
  constexpr int NT = N/32;
  int mt = wave>>1, ntb = (wave&1)*NT;
  int r0 = blk*32;
  f32x4 acc[NT];
  #pragma unroll
  for (int nt=0; nt<NT; ++nt) acc[nt] = (f32x4){0.f,0.f,0.f,0.f};
  size_t arow = aoff + (size_t)(r0 + mt*16 + lm)*K + q*8;
  #pragma unroll
  for (int ks = 0; ks < K/32; ++ks){
    short8 a;
    if (AF32){
      const float* af = (const float*)A0 + arow + ks*32;
      float4 f0 = *(const float4*)af;
      float4 f1 = *(const float4*)(af + 4);
      a[0]=(short)f2bf(f0.x); a[1]=(short)f2bf(f0.y);
      a[2]=(short)f2bf(f0.z); a[3]=(short)f2bf(f0.w);
      a[4]=(short)f2bf(f1.x); a[5]=(short)f2bf(f1.y);
      a[6]=(short)f2bf(f1.z); a[7]=(short)f2bf(f1.w);
    } else {
      a = *(const short8*)((const u16*)A0 + arow + ks*32);
    }
    #pragma unroll
    for (int nt = 0; nt < NT; ++nt){
      short8 b;
      #pragma unroll
      for (int j = 0; j < 8; ++j)
        b[j] = (short)bl[(ks*32 + q*8 + j)*SROW + (ntb+nt)*16 + lm];
      acc[nt] = __builtin_amdgcn_mfma_f32_16x16x32_bf16(a, b, acc[nt], 0, 0, 0);
    }
  }
  #pragma unroll
  for (int nt = 0; nt < NT; ++nt)
    #pragma unroll
    for (int r = 0; r < 4; ++r){
      int row = r0 + mt*16 + q*4 + r;       // C/D: col=lane&15, row=quad*4+reg (m89)
      int col = (ntb+nt)*16 + lm;
      size_t idx = co + (size_t)row*N + col;
      if (C32){
        float hg = acc[nt][r];
        if (FUSE){
          __builtin_nontemporal_store(hg, &((float*)Cv)[idx]);  // hg: streaming
          float hv = gcn0[idx] + hg;
          hsum0[idx] += hv;
          hbf0[idx] = f2bf(hv);
        } else {
          ((float*)Cv)[idx] = hg;
        }
      } else {
        ((u16*)Cv)[idx] = f2bf(acc[nt][r]);
      }
    }
}

template<int K, int N, bool C32, bool FUSE>
__global__ __launch_bounds__(256) void k_gemm_tall(const u16* __restrict__ A0,
                                                   const float* __restrict__ Bu,
                                                   const float* __restrict__ Bi,
                                                   void* __restrict__ Cv,
                                                   const float* __restrict__ gcn0,
                                                   float* __restrict__ hsum0,
                                                   u16* __restrict__ hbf0,
                                                   int ublocks){
  __shared__ u32 blds[K*(N+2)/2];
  gemm_body<K,N,C32,FUSE,false>((int)blockIdx.x, A0, Bu, Bi, Cv, gcn0, hsum0, hbf0, ublocks, blds);
}

// k_f1: rank (returning-atomic flood, CU pipes idle) || hyper GEMM (MFMA,
// reads emb fp32 directly -- no dependency on init) || init (streaming).
// All three independent; GEMM+init hide under rank's ~235us atomic wall.
__global__ __launch_bounds__(256) void k_f1(const float* __restrict__ ue,
                                            const float* __restrict__ ie,
                                            u16* __restrict__ h_bf,
                                            float* __restrict__ hsum,
                                            const int* __restrict__ rows_,
                                            int* __restrict__ cnt,
                                            int* __restrict__ rank_e,
                                            const float* __restrict__ user_w,
                                            const float* __restrict__ item_w,
                                            u16* __restrict__ hyper){
  __shared__ u32 blds[64*(HYP+2)/2];
  int bid = blockIdx.x;
  if (bid < NB_E4){
    // rank: rank_e[e] = #prior edges with same row (returning atomics; result
    // stored sequentially). 4M device-scope RMWs -> fabric-throughput-bound.
    int t = bid*256 + threadIdx.x;
    int e = t*4;
    if (e >= NNZ) return;                     // NNZ%4==0: int4 load is safe
    int4 r4 = *(const int4*)(rows_ + e);
    int4 k;
    k.x = atomicAdd(&cnt[min(max(r4.x,0),N_NODES-1)], 1);
    k.y = atomicAdd(&cnt[min(max(r4.y,0),N_NODES-1)], 1);
    k.z = atomicAdd(&cnt[min(max(r4.z,0),N_NODES-1)], 1);
    k.w = atomicAdd(&cnt[min(max(r4.w,0),N_NODES-1)], 1);
    *(int4*)(rank_e + e) = k;
    return;
  }
  if (bid < NB_E4 + NB_GEMM){
    // hyper = bf16(emb) @ bf16(w), A read from fp32 emb (user|item split)
    int gb = bid - NB_E4;
    const void* A0 = (gb < UB64) ? (const void*)ue
                                 : (const void*)(ie - (size_t)UB64*32*64);
    // note: item segment A-offset aoff=UB64*32*64 applied inside gemm_body;
    // pass ie rebased so aoff lands at ie[0].
    gemm_body<64,HYP,false,false,true>(gb, A0, user_w, item_w, hyper,
                                       nullptr, nullptr, nullptr, UB64, blds);
    return;
  }
  init_body((bid - NB_E4 - NB_GEMM)*256 + threadIdx.x, ue, ie, h_bf, hsum);
}

// ---------------- step3: partial tiles (no hot atomics) ----------------------
__device__ __forceinline__ void step3_body(const u16* __restrict__ Hy,
                                           const u16* __restrict__ Hm,
                                           float* __restrict__ outp, int rows, int k0,
                                           u32* __restrict__ lds){
  u32* hyl = lds;            // 32 k-rows x 128 elems, stride 130 u16 (65 u32)
  u32* hml = lds + 32*65;    // 32 k-rows x 64 elems,  stride 66 u16 (33 u32)
  const u16* hyl16 = (const u16*)hyl;
  const u16* hml16 = (const u16*)hml;
  int tid = threadIdx.x;
  int wave = tid>>6, lane = tid&63, q = lane>>4, lm = lane&15;
  f32x4 acc[2][4];
  #pragma unroll
  for (int i=0;i<2;i++)
    #pragma unroll
    for (int j=0;j<4;j++) acc[i][j] = (f32x4){0.f,0.f,0.f,0.f};
  for (int kk=0; kk<S3_CHUNK/32; ++kk){
    int kb = k0 + kk*32;
    #pragma unroll
    for (int d0=0; d0<8; ++d0){
      int d = d0*256 + tid;
      int kr = d>>6, c2 = d&63, g = kb+kr;
      hyl[kr*65 + c2] = (g < rows) ? ((const u32*)Hy)[(size_t)g*64 + c2] : 0u;
    }
    #pragma unroll
    for (int d0=0; d0<4; ++d0){
      int d = d0*256 + tid;
      int kr = d>>5, c2 = d&31, g = kb+kr;
      hml[kr*33 + c2] = (g < rows) ? ((const u32*)Hm)[(size_t)g*32 + c2] : 0u;
    }
    __syncthreads();
    short8 a[2], b[4];
    #pragma unroll
    for (int ml=0; ml<2; ++ml)
      #pragma unroll
      for (int j=0;j<8;j++)
        a[ml][j] = (short)hyl16[(q*8+j)*130 + (wave*2+ml)*16 + lm];  // A[m][k]=Hy[k][m]
    #pragma unroll
    for (int nt=0; nt<4; ++nt)
      #pragma unroll
      for (int j=0;j<8;j++)
        b[nt][j] = (short)hml16[(q*8+j)*66 + nt*16 + lm];            // B[k][n]=Hm[k][n]
    #pragma unroll
    for (int ml=0; ml<2; ++ml)
      #pragma unroll
      for (int nt=0; nt<4; ++nt)
        acc[ml][nt] = __builtin_amdgcn_mfma_f32_16x16x32_bf16(a[ml], b[nt], acc[ml][nt], 0,0,0);
    __syncthreads();
  }
  #pragma unroll
  for (int ml=0; ml<2; ++ml)
    #pragma unroll
    for (int nt=0; nt<4; ++nt)
      #pragma unroll
      for (int r=0;r<4;r++){
        int m = (wave*2+ml)*16 + q*4 + r;
        int n = nt*16 + lm;
        __builtin_nontemporal_store(acc[ml][nt][r], &outp[m*64 + n]);
      }
}

__device__ __forceinline__ void step3_dispatch(int bid, const u16* __restrict__ hyper,
                                               const u16* __restrict__ h,
                                               float* __restrict__ part, u32* lds){
  float* outp = part + (size_t)bid*8192;
  if (bid < NB_S3U)
    step3_body(hyper, h, outp, N_USERS, bid*S3_CHUNK, lds);
  else
    step3_body(hyper + (size_t)N_USERS*HYP, h + (size_t)N_USERS*D,
               outp, N_ITEMS, (bid - NB_S3U)*S3_CHUNK, lds);
}

// k_f2: place (random-store flood) || step3(layer 0) (MFMA/LDS) -- independent.
__global__ __launch_bounds__(256) void k_f2(const int* __restrict__ rows_,
                                            const int* __restrict__ cols_,
                                            const float* __restrict__ vals_,
                                            const int* __restrict__ rank_e,
                                            const int* __restrict__ rowptr,
                                            int2* __restrict__ pair_s,
                                            const u16* __restrict__ hyper,
                                            const u16* __restrict__ h_bf,
                                            float* __restrict__ part){
  __shared__ u32 lds[32*65 + 32*33];
  int bid = blockIdx.x;
  if (bid < NB_E4){
    // place: p = rowptr[row] + rank. Atomic-free; one 8B packed nontemporal
    // store per edge (random lines, zero reuse -> bypass L2 allocation).
    int t = bid*256 + threadIdx.x;
    int e = t*4;
    if (e >= NNZ) return;
    int4 r4 = *(const int4*)(rows_ + e);
    int4 k4 = *(const int4*)(rank_e + e);
    int4 c4 = *(const int4*)(cols_ + e);
    float4 v4 = *(const float4*)(vals_ + e);
    int p; u64 pk;
    p = rowptr[min(max(r4.x,0),N_NODES-1)] + k4.x; p = min(max(p,0),NNZ-1);
    pk = (u64)(u32)c4.x | ((u64)(u32)__float_as_int(v4.x) << 32);
    __builtin_nontemporal_store(pk, (u64*)&pair_s[p]);
    p = rowptr[min(max(r4.y,0),N_NODES-1)] + k4.y; p = min(max(p,0),NNZ-1);
    pk = (u64)(u32)c4.y | ((u64)(u32)__float_as_int(v4.y) << 32);
    __builtin_nontemporal_store(pk, (u64*)&pair_s[p]);
    p = rowptr[min(max(r4.z,0),N_NODES-1)] + k4.z; p = min(max(p,0),NNZ-1);
    pk = (u64)(u32)c4.z | ((u64)(u32)__float_as_int(v4.z) << 32);
    __builtin_nontemporal_store(pk, (u64*)&pair_s[p]);
    p = rowptr[min(max(r4.w,0),N_NODES-1)] + k4.w; p = min(max(p,0),NNZ-1);
    pk = (u64)(u32)c4.w | ((u64)(u32)__float_as_int(v4.w) << 32);
    __builtin_nontemporal_store(pk, (u64*)&pair_s[p]);
    return;
  }
  step3_dispatch(bid - NB_E4, hyper, h_bf, part, lds);
}

// spmm body: one wave per row; 8-deep independent gather pipeline.
__device__ __forceinline__ void spmm_body(int r, const int* __restrict__ rp,
                                          const int2* __restrict__ ps,
                                          const u16* __restrict__ h,
                                          float* __restrict__ gout){
  int lane = threadIdx.x & 63;
  int beg = rp[r], end = rp[r+1];
  float acc = 0.f;
  for (int base = beg; base < end; base += 64){
    int c = 0; float v = 0.f;
    if (base + lane < end){ int2 pv = ps[base+lane]; c = pv.x; v = __int_as_float(pv.y); }
    int n = end - base; if (n > 64) n = 64;
    for (int e = 0; e < n; e += 8){
      int ce[8]; float ve[8]; float hv[8];
      #pragma unroll
      for (int j = 0; j < 8; ++j){
        ce[j] = __shfl(c, e + j);
        ve[j] = __shfl(v, e + j);
      }
      #pragma unroll
      for (int j = 0; j < 8; ++j)
        hv[j] = bf2f(h[(size_t)ce[j]*64 + lane]);   // 8 independent gathers
      #pragma unroll
      for (int j = 0; j < 8; ++j)
        acc += ve[j] * hv[j];
    }
  }
  gout[(size_t)r*64 + lane] = acc;
}

__global__ __launch_bounds__(256) void k_spmm(const int* __restrict__ rp,
                                              const int2* __restrict__ ps,
                                              const u16* __restrict__ h,
                                              float* __restrict__ gout){
  spmm_body(blockIdx.x*4 + (threadIdx.x>>6), rp, ps, h, gout);
}

// Layer-1 fused: step3 blocks first (MFMA, ~40us, atomic-free now), spmm after.
__global__ __launch_bounds__(256) void k_layer(const int* __restrict__ rp,
                                               const int2* __restrict__ ps,
                                               const u16* __restrict__ h,
                                               float* __restrict__ gout,
                                               const u16* __restrict__ hyper,
                                               float* __restrict__ part){
  __shared__ u32 lds[32*65 + 32*33];
  int bid = blockIdx.x;
  if (bid < NB_S3){
    step3_dispatch(bid, hyper, h, part, lds);
    return;
  }
  spmm_body((bid - NB_S3)*4 + (threadIdx.x>>6), rp, ps, h, gout);
}

// Sum the 587 partial tiles into tmp[2][8192] (32-block groups, 1 atomic/thread).
__global__ void k_reduce(const float* __restrict__ part, float* __restrict__ tmp){
  int cb = blockIdx.x & 31;           // 32 col-blocks x 256 threads = 8192 cols
  int g  = blockIdx.x >> 5;           // group 0..RG_U+RG_I-1
  int j  = cb*256 + threadIdx.x;
  int b0, b1; float* dst;
  if (g < RG_U){ b0 = g*32;            b1 = min(b0+32, NB_S3U); dst = tmp; }
  else         { b0 = NB_S3U + (g-RG_U)*32; b1 = min(b0+32, NB_S3); dst = tmp + HYP*D; }
  float s = 0.f;
  for (int b = b0; b < b1; ++b) s += part[(size_t)b*8192 + j];
  atomicAdd(&dst[j], s);
}

// ---------------- scans (unchanged) ------------------------------------------
__global__ __launch_bounds__(1024) void k_scan1(const int* __restrict__ cnt,
                                                int* __restrict__ rowptr, int* __restrict__ bsum){
  __shared__ int lds[1024];
  int i = blockIdx.x*1024 + threadIdx.x;
  int v = (i < N_NODES) ? cnt[i] : 0;
  lds[threadIdx.x] = v;
  for (int off=1; off<1024; off<<=1){
    __syncthreads();
    int add = (threadIdx.x >= off) ? lds[threadIdx.x-off] : 0;
    __syncthreads();
    lds[threadIdx.x] += add;
  }
  if (i < N_NODES) rowptr[i+1] = lds[threadIdx.x];
  if (threadIdx.x == 1023) bsum[blockIdx.x] = lds[1023];
}

__global__ __launch_bounds__(1024) void k_scan2(const int* __restrict__ bsum,
                                                int* __restrict__ boff, int nb){
  __shared__ int lds[1024];
  int t = threadIdx.x;
  int v = (t < nb) ? bsum[t] : 0;
  lds[t] = v;
  for (int off=1; off<1024; off<<=1){
    __syncthreads();
    int add = (t >= off) ? lds[t-off] : 0;
    __syncthreads();
    lds[t] += add;
  }
  if (t < nb) boff[t] = lds[t] - v;   // exclusive offsets
}

__global__ void k_scan3(const int* __restrict__ cnt, int* __restrict__ rowptr,
                        const int* __restrict__ boff){
  int i = blockIdx.x*256 + threadIdx.x;
  if (i == 0) rowptr[0] = 0;
  if (i < N_NODES)
    rowptr[i+1] = rowptr[i+1] + boff[i>>10];
}

extern "C" void kernel_launch(void* const* d_in, const int* in_sizes, int n_in,
                              void* d_out, int out_size, void* d_ws, size_t ws_size,
                              hipStream_t stream) {
  const float* user_emb = (const float*)d_in[0];
  const float* item_emb = (const float*)d_in[1];
  const float* user_w   = (const float*)d_in[2];
  const float* item_w   = (const float*)d_in[3];
  const float* adj_vals = (const float*)d_in[4];
  const int* adj_rows = (const int*)d_in[5];
  const int* adj_cols = (const int*)d_in[6];
  float* out = (float*)d_out;

  // ws usage (~118 MB): hyper 76.8M + h_bf 38.4M + CSR misc ~2.5M
  char* w = (char*)d_ws;
  auto alloc = [&](size_t b){ void* p = (void*)w; w += (b + 255) & ~(size_t)255; return p; };
  u16*   hyper = (u16*)  alloc((size_t)N_NODES*HYP*2);
  u16*   h_bf  = (u16*)  alloc((size_t)N_NODES*D*2);
  int*   cnt   = (int*)  alloc((size_t)N_NODES*4);
  int*   rowptr= (int*)  alloc((size_t)(N_NODES+1)*4);
  int*   bsum  = (int*)  alloc(1024*4);
  int*   boff  = (int*)  alloc(1024*4);
  float* tmp_u = (float*)alloc((size_t)HYP*D*4);   // tmp_i = tmp_u + HYP*D
  float* tmp_i = (float*)alloc((size_t)HYP*D*4);
  (void)tmp_i;

  // Overlays on out (regions free until noted launch):
  int2*  pair_s = (int2*)(out + OUT_PAIR);         // hgnn[1]: free until gemm1
  float* part   = out + OUT_PART;                  // after pair_s, same region
  int*   rank_e = (int*) (out + OUT_RANK);         // gcn[1]: free until k_layer
  float* hsum   = out;                             // fp32 hidden-sum accumulator

  hipMemsetAsync(cnt, 0, (size_t)N_NODES*4, stream);
  hipMemsetAsync(tmp_u, 0, (size_t)2*HYP*D*4, stream);   // for layer-0 reduce

  // rank (atomic flood) || hyper-GEMM (emb fp32 direct) || init (streaming)
  k_f1<<<NB_E4 + NB_GEMM + NB_INIT, 256, 0, stream>>>(
      user_emb, item_emb, h_bf, hsum, adj_rows, cnt, rank_e,
      user_w, item_w, hyper);

  int nb1 = (N_NODES+1023)/1024;
  k_scan1<<<nb1, 1024, 0, stream>>>(cnt, rowptr, bsum);
  k_scan2<<<1, 1024, 0, stream>>>(bsum, boff, nb1);
  k_scan3<<<(N_NODES+255)/256, 256, 0, stream>>>(cnt, rowptr, boff);

  // place (random-store flood) || step3 layer 0 (MFMA)
  k_f2<<<NB_E4 + NB_S3, 256, 0, stream>>>(adj_rows, adj_cols, adj_vals, rank_e,
                                          rowptr, pair_s, hyper, h_bf, part);
  k_reduce<<<32*(RG_U+RG_I), 256, 0, stream>>>(part, tmp_u);

  // layer 0: spmm, then fused hg GEMM + epilogue
  k_spmm<<<NB_SPMM, 256, 0, stream>>>(rowptr, pair_s, h_bf, out + OUT_GCN0);
  k_gemm_tall<128,64,true,true><<<NB_GEMM, 256, 0, stream>>>(
      hyper, tmp_u, tmp_u + HYP*D, out + OUT_HG0, out + OUT_GCN0, hsum, h_bf, UB64);

  // layer 1: spmm || step3 (fused, atomic-free), reduce, fused GEMM + epilogue
  hipMemsetAsync(tmp_u, 0, (size_t)2*HYP*D*4, stream);
  k_layer<<<NB_S3 + NB_SPMM, 256, 0, stream>>>(rowptr, pair_s, h_bf,
                                               out + OUT_GCN0 + SZL, hyper, part);
  k_reduce<<<32*(RG_U+RG_I), 256, 0, stream>>>(part, tmp_u);
  k_gemm_tall<128,64,true,true><<<NB_GEMM, 256, 0, stream>>>(
      hyper, tmp_u, tmp_u + HYP*D, out + OUT_HG0 + SZL, out + OUT_GCN0 + SZL,
      hsum, h_bf, UB64);
}

// Round 7
// 1022.764 us; speedup vs baseline: 1.2178x; 1.2178x over previous
//
#include <hip/hip_runtime.h>

typedef unsigned short u16;
typedef unsigned int u32;
typedef unsigned long long u64;

#define N_USERS 100000
#define N_ITEMS 200000
#define N_NODES 300000
#define D 64
#define HYP 128
#define NNZ 4000000

// out is 96M fp32 elems: [user_out|item_out|gcn_hidden(2)|hgnn_hidden(2)]
constexpr long long SZL      = 19200000LL;        // one 300000x64 tensor
constexpr long long OUT_GCN0 = SZL;               // gcn_hidden base
constexpr long long OUT_HG0  = 3*SZL;             // hgnn_hidden base
// CSR {col,val} pairs overlaid on hgnn[l=1] region [4*SZL,5*SZL): last read by
// layer-1 spmm; hgnn[1] written only by the final fused GEMM after that.
constexpr long long OUT_PAIR = 4*SZL;
// step3 partial tiles (587 x 8192 floats = 19.2MB) after pair_s, same region.
constexpr long long OUT_PART = OUT_PAIR + 8000000LL;
// bin (bucketed edges, NNZ int2 = 32MB) overlaid on gcn_hidden[l=1] region
// [2*SZL,3*SZL): consumed by k_bfin during CSR build, long before layer-1
// spmm writes gcn[1].
constexpr long long OUT_BIN  = 2*SZL;

// ---- bucketed CSR build geometry ----
#define BSHIFT 10
#define RPB 1024                                   // rows per bucket
constexpr int NBKT = (N_NODES + RPB - 1)/RPB;      // 293 buckets
#define EPB 8192                                   // edges per stage-1 block
constexpr int NB_H = (NNZ + EPB - 1)/EPB;          // 489 stage-1 blocks

#define S3_CHUNK 512
constexpr int NB_S3U = (N_USERS + S3_CHUNK - 1)/S3_CHUNK;  // 196
constexpr int NB_S3I = (N_ITEMS + S3_CHUNK - 1)/S3_CHUNK;  // 391
constexpr int NB_S3  = NB_S3U + NB_S3I;                    // 587
constexpr int UB64   = N_USERS/32;                         // 3125 user gemm blocks
constexpr int NB_GEMM= N_NODES/32;                         // 9375
constexpr int NB_INIT= 9375;                               // init blocks
constexpr int NB_SPMM= N_NODES/4;                          // 75000
constexpr int RG_U   = (NB_S3U + 31)/32;                   // 7 reduce groups (user)
constexpr int RG_I   = (NB_S3I + 31)/32;                   // 13 reduce groups (item)

typedef __attribute__((ext_vector_type(8))) short short8;
typedef __attribute__((ext_vector_type(4))) float f32x4;

__device__ __forceinline__ float bf2f(u16 u){ u32 i = ((u32)u) << 16; return __builtin_bit_cast(float, i); }
__device__ __forceinline__ u16 f2bf(float f){
  u32 i = __builtin_bit_cast(u32, f);
  return (u16)((i + 0x7FFFu + ((i >> 16) & 1u)) >> 16);
}

// ---------------- init body: emb (fp32) -> h_bf (bf16), hsum (fp32) ----------
__device__ __forceinline__ void init_body(int t, const float* __restrict__ ue,
                                          const float* __restrict__ ie,
                                          u16* __restrict__ h_bf, float* __restrict__ hsum){
  int base = t*8;
  const float* src = (base < N_USERS*D) ? (ue + base) : (ie + (base - N_USERS*D));
  float4 v0 = *(const float4*)(src);
  float4 v1 = *(const float4*)(src + 4);
  *(float4*)(hsum + base)     = v0;
  *(float4*)(hsum + base + 4) = v1;
  uint4 p;
  p.x = (u32)f2bf(v0.x) | ((u32)f2bf(v0.y)<<16);
  p.y = (u32)f2bf(v0.z) | ((u32)f2bf(v0.w)<<16);
  p.z = (u32)f2bf(v1.x) | ((u32)f2bf(v1.y)<<16);
  p.w = (u32)f2bf(v1.z) | ((u32)f2bf(v1.w)<<16);
  *(uint4*)(h_bf + base) = p;
}

// ---------------- GEMM body ---------------------------------------------------
// C[M x N] = A[M x K] @ B[K x N]; A row-major bf16 (AF32=false) or fp32
// converted on the fly with the same f2bf rounding (AF32=true, bit-identical).
// B fp32 staged in LDS as bf16. 32 rows/block, 4 waves. User+item merged.
// FUSE: layer epilogue h = gcn+hg; hsum += h; hbf = bf16(h); hg nontemporal.
template<int K, int N, bool C32, bool FUSE, bool AF32>
__device__ __forceinline__ void gemm_body(int bid, const void* __restrict__ A0,
                                          const float* __restrict__ Bu,
                                          const float* __restrict__ Bi,
                                          void* __restrict__ Cv,
                                          const float* __restrict__ gcn0,
                                          float* __restrict__ hsum0,
                                          u16* __restrict__ hbf0,
                                          int ublocks, u32* blds){
  bool it = bid >= ublocks;
  int blk = it ? bid - ublocks : bid;
  const float* B = it ? Bi : Bu;
  size_t aoff = it ? (size_t)ublocks*32*K : 0;
  size_t co   = it ? (size_t)ublocks*32*N : 0;

  constexpr int SROW = N + 2;                 // padded u16 stride (odd dword stride)
  constexpr int PAIRS = K*N/2;
  for (int p = threadIdx.x; p < PAIRS; p += 256){
    int k = p/(N/2), c2 = p%(N/2);
    float f0 = B[2*p], f1 = B[2*p+1];
    blds[k*(SROW/2) + c2] = (u32)f2bf(f0) | ((u32)f2bf(f1)<<16);
  }
  __syncthreads();
  const u16* bl = (const u16*)blds;
  int wave = threadIdx.x>>6, lane = threadIdx.x&63, q = lane>>4, lm = lane&15;
  constexpr int NT = N/32;
  int mt = wave>>1, ntb = (wave&1)*NT;
  int r0 = blk*32;
  f32x4 acc[NT];
  #pragma unroll
  for (int nt=0; nt<NT; ++nt) acc[nt] = (f32x4){0.f,0.f,0.f,0.f};
  size_t arow = aoff + (size_t)(r0 + mt*16 + lm)*K + q*8;
  #pragma unroll
  for (int ks = 0; ks < K/32; ++ks){
    short8 a;
    if (AF32){
      const float* af = (const float*)A0 + arow + ks*32;
      float4 f0 = *(const float4*)af;
      float4 f1 = *(const float4*)(af + 4);
      a[0]=(short)f2bf(f0.x); a[1]=(short)f2bf(f0.y);
      a[2]=(short)f2bf(f0.z); a[3]=(short)f2bf(f0.w);
      a[4]=(short)f2bf(f1.x); a[5]=(short)f2bf(f1.y);
      a[6]=(short)f2bf(f1.z); a[7]=(short)f2bf(f1.w);
    } else {
      a = *(const short8*)((const u16*)A0 + arow + ks*32);
    }
    #pragma unroll
    for (int nt = 0; nt < NT; ++nt){
      short8 b;
      #pragma unroll
      for (int j = 0; j < 8; ++j)
        b[j] = (short)bl[(ks*32 + q*8 + j)*SROW + (ntb+nt)*16 + lm];
      acc[nt] = __builtin_amdgcn_mfma_f32_16x16x32_bf16(a, b, acc[nt], 0, 0, 0);
    }
  }
  #pragma unroll
  for (int nt = 0; nt < NT; ++nt)
    #pragma unroll
    for (int r = 0; r < 4; ++r){
      int row = r0 + mt*16 + q*4 + r;       // C/D: col=lane&15, row=quad*4+reg (m89)
      int col = (ntb+nt)*16 + lm;
      size_t idx = co + (size_t)row*N + col;
      if (C32){
        float hg = acc[nt][r];
        if (FUSE){
          __builtin_nontemporal_store(hg, &((float*)Cv)[idx]);  // hg: streaming
          float hv = gcn0[idx] + hg;
          hsum0[idx] += hv;
          hbf0[idx] = f2bf(hv);
        } else {
          ((float*)Cv)[idx] = hg;
        }
      } else {
        ((u16*)Cv)[idx] = f2bf(acc[nt][r]);
      }
    }
}

template<int K, int N, bool C32, bool FUSE>
__global__ __launch_bounds__(256) void k_gemm_tall(const u16* __restrict__ A0,
                                                   const float* __restrict__ Bu,
                                                   const float* __restrict__ Bi,
                                                   void* __restrict__ Cv,
                                                   const float* __restrict__ gcn0,
                                                   float* __restrict__ hsum0,
                                                   u16* __restrict__ hbf0,
                                                   int ublocks){
  __shared__ u32 blds[K*(N+2)/2];
  gemm_body<K,N,C32,FUSE,false>((int)blockIdx.x, A0, Bu, Bi, Cv, gcn0, hsum0, hbf0, ublocks, blds);
}

// k_front: bucket-histogram (LDS atomics only) || hyper GEMM (emb fp32 direct,
// no init dependency) || init (streaming). All independent throughput work.
__global__ __launch_bounds__(256) void k_front(const float* __restrict__ ue,
                                               const float* __restrict__ ie,
                                               u16* __restrict__ h_bf,
                                               float* __restrict__ hsum,
                                               const int* __restrict__ rows_,
                                               int* __restrict__ cnt_bb,
                                               const float* __restrict__ user_w,
                                               const float* __restrict__ item_w,
                                               u16* __restrict__ hyper){
  __shared__ u32 shmem[64*(HYP+2)/2];     // 16.6KB; bhist aliases first 293 ints
  int bid = blockIdx.x;
  int tid = threadIdx.x;
  if (bid < NB_H){
    int* hist = (int*)shmem;
    for (int i = tid; i < NBKT; i += 256) hist[i] = 0;
    __syncthreads();
    #pragma unroll
    for (int it = 0; it < 8; ++it){
      int e4 = bid*EPB + it*1024 + tid*4;
      if (e4 < NNZ){
        int4 r4 = *(const int4*)(rows_ + e4);
        atomicAdd(&hist[min(max(r4.x,0),N_NODES-1)>>BSHIFT], 1);
        atomicAdd(&hist[min(max(r4.y,0),N_NODES-1)>>BSHIFT], 1);
        atomicAdd(&hist[min(max(r4.z,0),N_NODES-1)>>BSHIFT], 1);
        atomicAdd(&hist[min(max(r4.w,0),N_NODES-1)>>BSHIFT], 1);
      }
    }
    __syncthreads();
    for (int i = tid; i < NBKT; i += 256) cnt_bb[i*NB_H + bid] = hist[i];
    return;
  }
  if (bid < NB_H + NB_GEMM){
    int gb = bid - NB_H;
    const void* A0 = (gb < UB64) ? (const void*)ue
                                 : (const void*)(ie - (size_t)UB64*32*64);
    gemm_body<64,HYP,false,false,true>(gb, A0, user_w, item_w, hyper,
                                       nullptr, nullptr, nullptr, UB64, shmem);
    return;
  }
  init_body((bid - NB_H - NB_GEMM)*256 + tid, ue, ie, h_bf, hsum);
}

// Exclusive-scan each bucket's row of cnt_bb over the 489 stage-1 blocks.
__global__ __launch_bounds__(256) void k_bscan(int* __restrict__ cnt_bb,
                                               int* __restrict__ btot){
  __shared__ int sA[512], sB[512];
  int b = blockIdx.x, tid = threadIdx.x;
  for (int i = tid; i < 512; i += 256) sA[i] = (i < NB_H) ? cnt_bb[b*NB_H + i] : 0;
  __syncthreads();
  int* cur = sA; int* nxt = sB;
  for (int off = 1; off < 512; off <<= 1){
    for (int i = tid; i < 512; i += 256)
      nxt[i] = cur[i] + ((i >= off) ? cur[i-off] : 0);
    __syncthreads();
    int* t = cur; cur = nxt; nxt = t;
  }
  for (int i = tid; i < NB_H; i += 256)
    cnt_bb[b*NB_H + i] = cur[i] - ((i < NB_H) ? 0 : 0) - cnt_bb[b*NB_H + i] + cnt_bb[b*NB_H + i] - cnt_bb[b*NB_H + i]; // placeholder avoided below
}

// NOTE: the line above is wrong-style; real implementation below re-reads orig.
__global__ __launch_bounds__(256) void k_bscan2(int* __restrict__ cnt_bb,
                                                int* __restrict__ btot){
  __shared__ int sA[512], sB[512];
  int b = blockIdx.x, tid = threadIdx.x;
  for (int i = tid; i < 512; i += 256) sA[i] = (i < NB_H) ? cnt_bb[b*NB_H + i] : 0;
  __syncthreads();
  int* cur = sA; int* nxt = sB;
  for (int off = 1; off < 512; off <<= 1){
    for (int i = tid; i < 512; i += 256)
      nxt[i] = cur[i] + ((i >= off) ? cur[i-off] : 0);
    __syncthreads();
    int* t = cur; cur = nxt; nxt = t;
  }
  // cur = inclusive scan; exclusive = inclusive - original (re-read original)
  for (int i = tid; i < NB_H; i += 256){
    int orig = cnt_bb[b*NB_H + i];        // still original? no: not yet written
    cnt_bb[b*NB_H + i] = cur[i] - orig;
  }
  if (tid == 0) btot[b] = cur[NB_H-1];
}

// Exclusive scan of btot[NBKT] -> bbase[NBKT+1] (bucket edge offsets).
__global__ __launch_bounds__(256) void k_bbase(const int* __restrict__ btot,
                                               int* __restrict__ bbase){
  __shared__ int sA[512], sB[512];
  int tid = threadIdx.x;
  for (int i = tid; i < 512; i += 256) sA[i] = (i < NBKT) ? btot[i] : 0;
  __syncthreads();
  int* cur = sA; int* nxt = sB;
  for (int off = 1; off < 512; off <<= 1){
    for (int i = tid; i < 512; i += 256)
      nxt[i] = cur[i] + ((i >= off) ? cur[i-off] : 0);
    __syncthreads();
    int* t = cur; cur = nxt; nxt = t;
  }
  for (int i = tid; i <= NBKT; i += 256)
    bbase[i] = (i == 0) ? 0 : cur[i-1];
}

// Bin edges by bucket: pack = (rowlocal<<19)|col (rowlocal<2^10, col<2^19).
__global__ __launch_bounds__(256) void k_bbin(const int* __restrict__ rows_,
                                              const int* __restrict__ cols_,
                                              const float* __restrict__ vals_,
                                              const int* __restrict__ cnt_bb,
                                              const int* __restrict__ bbase,
                                              int2* __restrict__ bin){
  __shared__ int cur[NBKT];
  int bid = blockIdx.x, tid = threadIdx.x;
  for (int i = tid; i < NBKT; i += 256)
    cur[i] = bbase[i] + cnt_bb[i*NB_H + bid];
  __syncthreads();
  #pragma unroll
  for (int it = 0; it < 8; ++it){
    int e4 = bid*EPB + it*1024 + tid*4;
    if (e4 < NNZ){
      int4 r4 = *(const int4*)(rows_ + e4);
      int4 c4 = *(const int4*)(cols_ + e4);
      float4 v4 = *(const float4*)(vals_ + e4);
      int rr[4] = {r4.x, r4.y, r4.z, r4.w};
      int cc[4] = {c4.x, c4.y, c4.z, c4.w};
      float vv[4] = {v4.x, v4.y, v4.z, v4.w};
      #pragma unroll
      for (int j = 0; j < 4; ++j){
        int r = min(max(rr[j],0), N_NODES-1);
        int c = min(max(cc[j],0), N_NODES-1);
        int pos = atomicAdd(&cur[r >> BSHIFT], 1);
        pos = min(max(pos,0), NNZ-1);
        int pack = ((r & (RPB-1)) << 19) | c;
        u64 pk = (u64)(u32)pack | ((u64)(u32)__float_as_int(vv[j]) << 32);
        __builtin_nontemporal_store(pk, (u64*)&bin[pos]);
      }
    }
  }
}

// Finalize: per bucket, LDS row-histogram -> LDS scan -> write rowptr ->
// LDS-cursor scatter of {col,val} into the bucket's L2-resident output range.
__global__ __launch_bounds__(256) void k_bfin(const int2* __restrict__ bin,
                                              const int* __restrict__ bbase,
                                              int* __restrict__ rowptr,
                                              int2* __restrict__ pair_s){
  __shared__ int s_hist[RPB];
  __shared__ int sA[RPB], sB[RPB];
  int b = blockIdx.x, tid = threadIdx.x;
  int ebeg = bbase[b], eend = bbase[b+1];
  int base = ebeg;
  for (int i = tid; i < RPB; i += 256) s_hist[i] = 0;
  __syncthreads();
  for (int e = ebeg + tid; e < eend; e += 256){
    int pack = bin[e].x;
    atomicAdd(&s_hist[(pack >> 19) & (RPB-1)], 1);
  }
  __syncthreads();
  for (int i = tid; i < RPB; i += 256) sA[i] = s_hist[i];
  __syncthreads();
  int* cur = sA; int* nxt = sB;
  for (int off = 1; off < RPB; off <<= 1){
    for (int i = tid; i < RPB; i += 256)
      nxt[i] = cur[i] + ((i >= off) ? cur[i-off] : 0);
    __syncthreads();
    int* t = cur; cur = nxt; nxt = t;
  }
  // cur = inclusive; cursor/rowptr value = base + (inclusive - hist) = exclusive
  int r0 = b << BSHIFT;
  for (int i = tid; i < RPB; i += 256){
    int v = base + cur[i] - s_hist[i];
    nxt[i] = v;                          // nxt reused as the scatter cursor
    if (r0 + i <= N_NODES) rowptr[r0 + i] = v;
  }
  __syncthreads();
  for (int e = ebeg + tid; e < eend; e += 256){
    int2 pv = bin[e];
    int rl = (pv.x >> 19) & (RPB-1);
    int c  = pv.x & 0x7FFFF;
    int pos = atomicAdd(&nxt[rl], 1);
    pos = min(max(pos,0), NNZ-1);
    pair_s[pos] = make_int2(c, pv.y);
  }
}

// ---------------- step3: partial tiles (no hot atomics) ----------------------
__device__ __forceinline__ void step3_body(const u16* __restrict__ Hy,
                                           const u16* __restrict__ Hm,
                                           float* __restrict__ outp, int rows, int k0,
                                           u32* __restrict__ lds){
  u32* hyl = lds;            // 32 k-rows x 128 elems, stride 130 u16 (65 u32)
  u32* hml = lds + 32*65;    // 32 k-rows x 64 elems,  stride 66 u16 (33 u32)
  const u16* hyl16 = (const u16*)hyl;
  const u16* hml16 = (const u16*)hml;
  int tid = threadIdx.x;
  int wave = tid>>6, lane = tid&63, q = lane>>4, lm = lane&15;
  f32x4 acc[2][4];
  #pragma unroll
  for (int i=0;i<2;i++)
    #pragma unroll
    for (int j=0;j<4;j++) acc[i][j] = (f32x4){0.f,0.f,0.f,0.f};
  for (int kk=0; kk<S3_CHUNK/32; ++kk){
    int kb = k0 + kk*32;
    #pragma unroll
    for (int d0=0; d0<8; ++d0){
      int d = d0*256 + tid;
      int kr = d>>6, c2 = d&63, g = kb+kr;
      hyl[kr*65 + c2] = (g < rows) ? ((const u32*)Hy)[(size_t)g*64 + c2] : 0u;
    }
    #pragma unroll
    for (int d0=0; d0<4; ++d0){
      int d = d0*256 + tid;
      int kr = d>>5, c2 = d&31, g = kb+kr;
      hml[kr*33 + c2] = (g < rows) ? ((const u32*)Hm)[(size_t)g*32 + c2] : 0u;
    }
    __syncthreads();
    short8 a[2], b[4];
    #pragma unroll
    for (int ml=0; ml<2; ++ml)
      #pragma unroll
      for (int j=0;j<8;j++)
        a[ml][j] = (short)hyl16[(q*8+j)*130 + (wave*2+ml)*16 + lm];  // A[m][k]=Hy[k][m]
    #pragma unroll
    for (int nt=0; nt<4; ++nt)
      #pragma unroll
      for (int j=0;j<8;j++)
        b[nt][j] = (short)hml16[(q*8+j)*66 + nt*16 + lm];            // B[k][n]=Hm[k][n]
    #pragma unroll
    for (int ml=0; ml<2; ++ml)
      #pragma unroll
      for (int nt=0; nt<4; ++nt)
        acc[ml][nt] = __builtin_amdgcn_mfma_f32_16x16x32_bf16(a[ml], b[nt], acc[ml][nt], 0,0,0);
    __syncthreads();
  }
  #pragma unroll
  for (int ml=0; ml<2; ++ml)
    #pragma unroll
    for (int nt=0; nt<4; ++nt)
      #pragma unroll
      for (int r=0;r<4;r++){
        int m = (wave*2+ml)*16 + q*4 + r;
        int n = nt*16 + lm;
        __builtin_nontemporal_store(acc[ml][nt][r], &outp[m*64 + n]);
      }
}

__global__ __launch_bounds__(256) void k_step3(const u16* __restrict__ hyper,
                                               const u16* __restrict__ h,
                                               float* __restrict__ part){
  __shared__ u32 lds[32*65 + 32*33];
  int bid = blockIdx.x;
  float* outp = part + (size_t)bid*8192;
  if (bid < NB_S3U)
    step3_body(hyper, h, outp, N_USERS, bid*S3_CHUNK, lds);
  else
    step3_body(hyper + (size_t)N_USERS*HYP, h + (size_t)N_USERS*D,
               outp, N_ITEMS, (bid - NB_S3U)*S3_CHUNK, lds);
}

// Sum the 587 partial tiles into tmp[2][8192] (32-block groups, 1 atomic/thread).
__global__ void k_reduce(const float* __restrict__ part, float* __restrict__ tmp){
  int cb = blockIdx.x & 31;           // 32 col-blocks x 256 threads = 8192 cols
  int g  = blockIdx.x >> 5;
  int j  = cb*256 + threadIdx.x;
  int b0, b1; float* dst;
  if (g < RG_U){ b0 = g*32;            b1 = min(b0+32, NB_S3U); dst = tmp; }
  else         { b0 = NB_S3U + (g-RG_U)*32; b1 = min(b0+32, NB_S3); dst = tmp + HYP*D; }
  float s = 0.f;
  for (int b = b0; b < b1; ++b) s += part[(size_t)b*8192 + j];
  atomicAdd(&dst[j], s);
}

// ---------------- spmm (standalone; 8-deep gather pipeline) ------------------
__global__ __launch_bounds__(256) void k_spmm(const int* __restrict__ rp,
                                              const int2* __restrict__ ps,
                                              const u16* __restrict__ h,
                                              float* __restrict__ gout){
  int r = blockIdx.x*4 + (threadIdx.x>>6);
  int lane = threadIdx.x & 63;
  int beg = rp[r], end = rp[r+1];
  float acc = 0.f;
  for (int base = beg; base < end; base += 64){
    int c = 0; float v = 0.f;
    if (base + lane < end){ int2 pv = ps[base+lane]; c = pv.x; v = __int_as_float(pv.y); }
    int n = end - base; if (n > 64) n = 64;
    for (int e = 0; e < n; e += 8){
      int ce[8]; float ve[8]; float hv[8];
      #pragma unroll
      for (int j = 0; j < 8; ++j){
        ce[j] = __shfl(c, e + j);
        ve[j] = __shfl(v, e + j);
      }
      #pragma unroll
      for (int j = 0; j < 8; ++j)
        hv[j] = bf2f(h[(size_t)ce[j]*64 + lane]);   // 8 independent gathers
      #pragma unroll
      for (int j = 0; j < 8; ++j)
        acc += ve[j] * hv[j];
    }
  }
  gout[(size_t)r*64 + lane] = acc;
}

extern "C" void kernel_launch(void* const* d_in, const int* in_sizes, int n_in,
                              void* d_out, int out_size, void* d_ws, size_t ws_size,
                              hipStream_t stream) {
  const float* user_emb = (const float*)d_in[0];
  const float* item_emb = (const float*)d_in[1];
  const float* user_w   = (const float*)d_in[2];
  const float* item_w   = (const float*)d_in[3];
  const float* adj_vals = (const float*)d_in[4];
  const int* adj_rows = (const int*)d_in[5];
  const int* adj_cols = (const int*)d_in[6];
  float* out = (float*)d_out;

  // ws (~117 MB): hyper 76.8M + h_bf 38.4M + rowptr 1.2M + cnt_bb 0.6M + misc
  char* w = (char*)d_ws;
  auto alloc = [&](size_t b){ void* p = (void*)w; w += (b + 255) & ~(size_t)255; return p; };
  u16*   hyper  = (u16*)  alloc((size_t)N_NODES*HYP*2);
  u16*   h_bf   = (u16*)  alloc((size_t)N_NODES*D*2);
  int*   rowptr = (int*)  alloc((size_t)(N_NODES+1)*4);
  int*   cnt_bb = (int*)  alloc((size_t)NBKT*NB_H*4);
  int*   btot   = (int*)  alloc((size_t)NBKT*4);
  int*   bbase  = (int*)  alloc((size_t)(NBKT+1)*4);
  float* tmp_u  = (float*)alloc((size_t)HYP*D*4);  // tmp_i = tmp_u + HYP*D
  float* tmp_i  = (float*)alloc((size_t)HYP*D*4);
  (void)tmp_i;

  // Overlays on out (regions free until noted launch):
  int2*  pair_s = (int2*)(out + OUT_PAIR);         // hgnn[1]: free until gemm1
  float* part   = out + OUT_PART;                  // after pair_s, same region
  int2*  bin    = (int2*)(out + OUT_BIN);          // gcn[1]: free until l1 spmm
  float* hsum   = out;                             // fp32 hidden-sum accumulator

  hipMemsetAsync(tmp_u, 0, (size_t)2*HYP*D*4, stream);   // for layer-0 reduce

  // bucket-hist (LDS atomics) || hyper-GEMM (emb fp32 direct) || init
  k_front<<<NB_H + NB_GEMM + NB_INIT, 256, 0, stream>>>(
      user_emb, item_emb, h_bf, hsum, adj_rows, cnt_bb, user_w, item_w, hyper);

  // CSR build: scan block-bucket matrix -> bucket offsets -> bin -> finalize
  k_bscan2<<<NBKT, 256, 0, stream>>>(cnt_bb, btot);
  k_bbase<<<1, 256, 0, stream>>>(btot, bbase);
  k_bbin<<<NB_H, 256, 0, stream>>>(adj_rows, adj_cols, adj_vals, cnt_bb, bbase, bin);
  k_bfin<<<NBKT, 256, 0, stream>>>(bin, bbase, rowptr, pair_s);

  // layer 0
  k_spmm<<<NB_SPMM, 256, 0, stream>>>(rowptr, pair_s, h_bf, out + OUT_GCN0);
  k_step3<<<NB_S3, 256, 0, stream>>>(hyper, h_bf, part);
  k_reduce<<<32*(RG_U+RG_I), 256, 0, stream>>>(part, tmp_u);
  k_gemm_tall<128,64,true,true><<<NB_GEMM, 256, 0, stream>>>(
      hyper, tmp_u, tmp_u + HYP*D, out + OUT_HG0, out + OUT_GCN0, hsum, h_bf, UB64);

  // layer 1
  hipMemsetAsync(tmp_u, 0, (size_t)2*HYP*D*4, stream);
  k_spmm<<<NB_SPMM, 256, 0, stream>>>(rowptr, pair_s, h_bf, out + OUT_GCN0 + SZL);
  k_step3<<<NB_S3, 256, 0, stream>>>(hyper, h_bf, part);
  k_reduce<<<32*(RG_U+RG_I), 256, 0, stream>>>(part, tmp_u);
  k_gemm_tall<128,64,true,true><<<NB_GEMM, 256, 0, stream>>>(
      hyper, tmp_u, tmp_u + HYP*D, out + OUT_HG0 + SZL, out + OUT_GCN0 + SZL,
      hsum, h_bf, UB64);
}

// Round 8
// 997.075 us; speedup vs baseline: 1.2492x; 1.0258x over previous
//
#include <hip/hip_runtime.h>

typedef unsigned short u16;
typedef unsigned int u32;
typedef unsigned long long u64;

#define N_USERS 100000
#define N_ITEMS 200000
#define N_NODES 300000
#define D 64
#define HYP 128
#define NNZ 4000000

// out is 96M fp32 elems: [user_out|item_out|gcn_hidden(2)|hgnn_hidden(2)]
constexpr long long SZL      = 19200000LL;        // one 300000x64 tensor
constexpr long long OUT_GCN0 = SZL;               // gcn_hidden base
constexpr long long OUT_HG0  = 3*SZL;             // hgnn_hidden base
// CSR {col,val} pairs overlaid on hgnn[l=1] region [4*SZL,5*SZL): last read by
// layer-1 spmm; hgnn[1] written only by the final fused GEMM after that.
constexpr long long OUT_PAIR = 4*SZL;
// step3 partial tiles (587 x 8192 floats = 19.2MB) after pair_s, same region.
constexpr long long OUT_PART = OUT_PAIR + 8000000LL;
// bin (bucketed edges, NNZ int2 = 32MB) overlaid on gcn_hidden[l=1] region
// [2*SZL,3*SZL): consumed by k_bfin, long before layer-1 spmm writes gcn[1].
constexpr long long OUT_BIN  = 2*SZL;

// ---- bucketed CSR build geometry ----
#define BSHIFT 10
#define RPB 1024                                   // rows per bucket
constexpr int NBKT = (N_NODES + RPB - 1)/RPB;      // 293 buckets
#define EPB 8192                                   // edges per stage-1 block
constexpr int NB_H = (NNZ + EPB - 1)/EPB;          // 489 stage-1 blocks

#define S3_CHUNK 512
constexpr int NB_S3U = (N_USERS + S3_CHUNK - 1)/S3_CHUNK;  // 196
constexpr int NB_S3I = (N_ITEMS + S3_CHUNK - 1)/S3_CHUNK;  // 391
constexpr int NB_S3  = NB_S3U + NB_S3I;                    // 587
constexpr int UB64   = N_USERS/32;                         // 3125 user gemm blocks
constexpr int NB_GEMM= N_NODES/32;                         // 9375
constexpr int NB_INIT= 9375;                               // init blocks
constexpr int NB_SPMM= N_NODES/4;                          // 75000
constexpr int NB_RED = 64;                                 // reduce blocks (32 user + 32 item)

typedef __attribute__((ext_vector_type(8))) short short8;
typedef __attribute__((ext_vector_type(4))) float f32x4;

__device__ __forceinline__ float bf2f(u16 u){ u32 i = ((u32)u) << 16; return __builtin_bit_cast(float, i); }
__device__ __forceinline__ u16 f2bf(float f){
  u32 i = __builtin_bit_cast(u32, f);
  return (u16)((i + 0x7FFFu + ((i >> 16) & 1u)) >> 16);
}

// ---------------- init body: emb (fp32) -> h_bf (bf16), hsum (fp32) ----------
__device__ __forceinline__ void init_body(int t, const float* __restrict__ ue,
                                          const float* __restrict__ ie,
                                          u16* __restrict__ h_bf, float* __restrict__ hsum){
  int base = t*8;
  const float* src = (base < N_USERS*D) ? (ue + base) : (ie + (base - N_USERS*D));
  float4 v0 = *(const float4*)(src);
  float4 v1 = *(const float4*)(src + 4);
  *(float4*)(hsum + base)     = v0;
  *(float4*)(hsum + base + 4) = v1;
  uint4 p;
  p.x = (u32)f2bf(v0.x) | ((u32)f2bf(v0.y)<<16);
  p.y = (u32)f2bf(v0.z) | ((u32)f2bf(v0.w)<<16);
  p.z = (u32)f2bf(v1.x) | ((u32)f2bf(v1.y)<<16);
  p.w = (u32)f2bf(v1.z) | ((u32)f2bf(v1.w)<<16);
  *(uint4*)(h_bf + base) = p;
}

// ---------------- GEMM body ---------------------------------------------------
// C[M x N] = A[M x K] @ B[K x N]; A row-major bf16 (AF32=false) or fp32
// converted on the fly with the same f2bf rounding (AF32=true, bit-identical).
// B fp32 staged in LDS as bf16. 32 rows/block, 4 waves. User+item merged.
// FUSE: layer epilogue h = gcn+hg; hsum += h; hbf = bf16(h); hg nontemporal.
template<int K, int N, bool C32, bool FUSE, bool AF32>
__device__ __forceinline__ void gemm_body(int bid, const void* __restrict__ A0,
                                          const float* __restrict__ Bu,
                                          const float* __restrict__ Bi,
                                          void* __restrict__ Cv,
                                          const float* __restrict__ gcn0,
                                          float* __restrict__ hsum0,
                                          u16* __restrict__ hbf0,
                                          int ublocks, u32* blds){
  bool it = bid >= ublocks;
  int blk = it ? bid - ublocks : bid;
  const float* B = it ? Bi : Bu;
  size_t aoff = it ? (size_t)ublocks*32*K : 0;
  size_t co   = it ? (size_t)ublocks*32*N : 0;

  constexpr int SROW = N + 2;                 // padded u16 stride (odd dword stride)
  constexpr int PAIRS = K*N/2;
  for (int p = threadIdx.x; p < PAIRS; p += 256){
    int k = p/(N/2), c2 = p%(N/2);
    float f0 = B[2*p], f1 = B[2*p+1];
    blds[k*(SROW/2) + c2] = (u32)f2bf(f0) | ((u32)f2bf(f1)<<16);
  }
  __syncthreads();
  const u16* bl = (const u16*)blds;
  int wave = threadIdx.x>>6, lane = threadIdx.x&63, q = lane>>4, lm = lane&15;
  constexpr int NT = N/32;
  int mt = wave>>1, ntb = (wave&1)*NT;
  int r0 = blk*32;
  f32x4 acc[NT];
  #pragma unroll
  for (int nt=0; nt<NT; ++nt) acc[nt] = (f32x4){0.f,0.f,0.f,0.f};
  size_t arow = aoff + (size_t)(r0 + mt*16 + lm)*K + q*8;
  #pragma unroll
  for (int ks = 0; ks < K/32; ++ks){
    short8 a;
    if (AF32){
      const float* af = (const float*)A0 + arow + ks*32;
      float4 f0 = *(const float4*)af;
      float4 f1 = *(const float4*)(af + 4);
      a[0]=(short)f2bf(f0.x); a[1]=(short)f2bf(f0.y);
      a[2]=(short)f2bf(f0.z); a[3]=(short)f2bf(f0.w);
      a[4]=(short)f2bf(f1.x); a[5]=(short)f2bf(f1.y);
      a[6]=(short)f2bf(f1.z); a[7]=(short)f2bf(f1.w);
    } else {
      a = *(const short8*)((const u16*)A0 + arow + ks*32);
    }
    #pragma unroll
    for (int nt = 0; nt < NT; ++nt){
      short8 b;
      #pragma unroll
      for (int j = 0; j < 8; ++j)
        b[j] = (short)bl[(ks*32 + q*8 + j)*SROW + (ntb+nt)*16 + lm];
      acc[nt] = __builtin_amdgcn_mfma_f32_16x16x32_bf16(a, b, acc[nt], 0, 0, 0);
    }
  }
  #pragma unroll
  for (int nt = 0; nt < NT; ++nt)
    #pragma unroll
    for (int r = 0; r < 4; ++r){
      int row = r0 + mt*16 + q*4 + r;       // C/D: col=lane&15, row=quad*4+reg (m89)
      int col = (ntb+nt)*16 + lm;
      size_t idx = co + (size_t)row*N + col;
      if (C32){
        float hg = acc[nt][r];
        if (FUSE){
          __builtin_nontemporal_store(hg, &((float*)Cv)[idx]);  // hg: streaming
          float hv = gcn0[idx] + hg;
          hsum0[idx] += hv;
          hbf0[idx] = f2bf(hv);
        } else {
          ((float*)Cv)[idx] = hg;
        }
      } else {
        ((u16*)Cv)[idx] = f2bf(acc[nt][r]);
      }
    }
}

template<int K, int N, bool C32, bool FUSE>
__global__ __launch_bounds__(256) void k_gemm_tall(const u16* __restrict__ A0,
                                                   const float* __restrict__ Bu,
                                                   const float* __restrict__ Bi,
                                                   void* __restrict__ Cv,
                                                   const float* __restrict__ gcn0,
                                                   float* __restrict__ hsum0,
                                                   u16* __restrict__ hbf0,
                                                   int ublocks){
  __shared__ u32 blds[K*(N+2)/2];
  gemm_body<K,N,C32,FUSE,false>((int)blockIdx.x, A0, Bu, Bi, Cv, gcn0, hsum0, hbf0, ublocks, blds);
}

// k_front: bucket-histogram (LDS atomics only) || hyper GEMM (emb fp32 direct,
// no init dependency) || init (streaming). All independent throughput work.
__global__ __launch_bounds__(256) void k_front(const float* __restrict__ ue,
                                               const float* __restrict__ ie,
                                               u16* __restrict__ h_bf,
                                               float* __restrict__ hsum,
                                               const int* __restrict__ rows_,
                                               int* __restrict__ cnt_bb,
                                               const float* __restrict__ user_w,
                                               const float* __restrict__ item_w,
                                               u16* __restrict__ hyper){
  __shared__ u32 shmem[64*(HYP+2)/2];     // 16.6KB; bucket hist aliases first 293 ints
  int bid = blockIdx.x;
  int tid = threadIdx.x;
  if (bid < NB_H){
    int* hist = (int*)shmem;
    for (int i = tid; i < NBKT; i += 256) hist[i] = 0;
    __syncthreads();
    #pragma unroll
    for (int it = 0; it < 8; ++it){
      int e4 = bid*EPB + it*1024 + tid*4;
      if (e4 < NNZ){
        int4 r4 = *(const int4*)(rows_ + e4);
        atomicAdd(&hist[min(max(r4.x,0),N_NODES-1)>>BSHIFT], 1);
        atomicAdd(&hist[min(max(r4.y,0),N_NODES-1)>>BSHIFT], 1);
        atomicAdd(&hist[min(max(r4.z,0),N_NODES-1)>>BSHIFT], 1);
        atomicAdd(&hist[min(max(r4.w,0),N_NODES-1)>>BSHIFT], 1);
      }
    }
    __syncthreads();
    for (int i = tid; i < NBKT; i += 256) cnt_bb[i*NB_H + bid] = hist[i];
    return;
  }
  if (bid < NB_H + NB_GEMM){
    int gb = bid - NB_H;
    const void* A0 = (gb < UB64) ? (const void*)ue
                                 : (const void*)(ie - (size_t)UB64*32*64);
    gemm_body<64,HYP,false,false,true>(gb, A0, user_w, item_w, hyper,
                                       nullptr, nullptr, nullptr, UB64, shmem);
    return;
  }
  init_body((bid - NB_H - NB_GEMM)*256 + tid, ue, ie, h_bf, hsum);
}

// Per-bucket exclusive scan of cnt_bb over the 489 stage-1 blocks.
__global__ __launch_bounds__(256) void k_bscan2(int* __restrict__ cnt_bb,
                                                int* __restrict__ btot){
  __shared__ int sO[512], sA[512], sB[512];
  int b = blockIdx.x, tid = threadIdx.x;
  for (int i = tid; i < 512; i += 256){
    int v = (i < NB_H) ? cnt_bb[b*NB_H + i] : 0;
    sO[i] = v; sA[i] = v;
  }
  __syncthreads();
  int* cur = sA; int* nxt = sB;
  for (int off = 1; off < 512; off <<= 1){
    for (int i = tid; i < 512; i += 256)
      nxt[i] = cur[i] + ((i >= off) ? cur[i-off] : 0);
    __syncthreads();
    int* t = cur; cur = nxt; nxt = t;
  }
  for (int i = tid; i < NB_H; i += 256)
    cnt_bb[b*NB_H + i] = cur[i] - sO[i];    // exclusive
  if (tid == 0) btot[b] = cur[NB_H-1];
}

// Exclusive scan of btot[NBKT] -> bbase[NBKT+1] (bucket edge offsets).
__global__ __launch_bounds__(256) void k_bbase(const int* __restrict__ btot,
                                               int* __restrict__ bbase){
  __shared__ int sA[512], sB[512];
  int tid = threadIdx.x;
  for (int i = tid; i < 512; i += 256) sA[i] = (i < NBKT) ? btot[i] : 0;
  __syncthreads();
  int* cur = sA; int* nxt = sB;
  for (int off = 1; off < 512; off <<= 1){
    for (int i = tid; i < 512; i += 256)
      nxt[i] = cur[i] + ((i >= off) ? cur[i-off] : 0);
    __syncthreads();
    int* t = cur; cur = nxt; nxt = t;
  }
  for (int i = tid; i <= NBKT; i += 256)
    bbase[i] = (i == 0) ? 0 : cur[i-1];
}

// ---------------- step3: partial tiles (no hot atomics) ----------------------
__device__ __forceinline__ void step3_body(const u16* __restrict__ Hy,
                                           const u16* __restrict__ Hm,
                                           float* __restrict__ outp, int rows, int k0,
                                           u32* __restrict__ lds){
  u32* hyl = lds;            // 32 k-rows x 128 elems, stride 130 u16 (65 u32)
  u32* hml = lds + 32*65;    // 32 k-rows x 64 elems,  stride 66 u16 (33 u32)
  const u16* hyl16 = (const u16*)hyl;
  const u16* hml16 = (const u16*)hml;
  int tid = threadIdx.x;
  int wave = tid>>6, lane = tid&63, q = lane>>4, lm = lane&15;
  f32x4 acc[2][4];
  #pragma unroll
  for (int i=0;i<2;i++)
    #pragma unroll
    for (int j=0;j<4;j++) acc[i][j] = (f32x4){0.f,0.f,0.f,0.f};
  for (int kk=0; kk<S3_CHUNK/32; ++kk){
    int kb = k0 + kk*32;
    #pragma unroll
    for (int d0=0; d0<8; ++d0){
      int d = d0*256 + tid;
      int kr = d>>6, c2 = d&63, g = kb+kr;
      hyl[kr*65 + c2] = (g < rows) ? ((const u32*)Hy)[(size_t)g*64 + c2] : 0u;
    }
    #pragma unroll
    for (int d0=0; d0<4; ++d0){
      int d = d0*256 + tid;
      int kr = d>>5, c2 = d&31, g = kb+kr;
      hml[kr*33 + c2] = (g < rows) ? ((const u32*)Hm)[(size_t)g*32 + c2] : 0u;
    }
    __syncthreads();
    short8 a[2], b[4];
    #pragma unroll
    for (int ml=0; ml<2; ++ml)
      #pragma unroll
      for (int j=0;j<8;j++)
        a[ml][j] = (short)hyl16[(q*8+j)*130 + (wave*2+ml)*16 + lm];  // A[m][k]=Hy[k][m]
    #pragma unroll
    for (int nt=0; nt<4; ++nt)
      #pragma unroll
      for (int j=0;j<8;j++)
        b[nt][j] = (short)hml16[(q*8+j)*66 + nt*16 + lm];            // B[k][n]=Hm[k][n]
    #pragma unroll
    for (int ml=0; ml<2; ++ml)
      #pragma unroll
      for (int nt=0; nt<4; ++nt)
        acc[ml][nt] = __builtin_amdgcn_mfma_f32_16x16x32_bf16(a[ml], b[nt], acc[ml][nt], 0,0,0);
    __syncthreads();
  }
  #pragma unroll
  for (int ml=0; ml<2; ++ml)
    #pragma unroll
    for (int nt=0; nt<4; ++nt)
      #pragma unroll
      for (int r=0;r<4;r++){
        int m = (wave*2+ml)*16 + q*4 + r;
        int n = nt*16 + lm;
        __builtin_nontemporal_store(acc[ml][nt][r], &outp[m*64 + n]);
      }
}

__device__ __forceinline__ void step3_dispatch(int bid, const u16* __restrict__ hyper,
                                               const u16* __restrict__ h,
                                               float* __restrict__ part, u32* lds){
  float* outp = part + (size_t)bid*8192;
  if (bid < NB_S3U)
    step3_body(hyper, h, outp, N_USERS, bid*S3_CHUNK, lds);
  else
    step3_body(hyper + (size_t)N_USERS*HYP, h + (size_t)N_USERS*D,
               outp, N_ITEMS, (bid - NB_S3U)*S3_CHUNK, lds);
}

__global__ __launch_bounds__(256) void k_step3(const u16* __restrict__ hyper,
                                               const u16* __restrict__ h,
                                               float* __restrict__ part){
  __shared__ u32 lds[32*65 + 32*33];
  step3_dispatch((int)blockIdx.x, hyper, h, part, lds);
}

// k_mid: bbin (LDS-cursor bucket scatter, store-flood) || step3 layer 0 (MFMA).
// Safe combo (k_f2 precedent); NOT the spmm-gather+step3 poison mix.
__global__ __launch_bounds__(256) void k_mid(const int* __restrict__ rows_,
                                             const int* __restrict__ cols_,
                                             const float* __restrict__ vals_,
                                             const int* __restrict__ cnt_bb,
                                             const int* __restrict__ bbase,
                                             int2* __restrict__ bin,
                                             const u16* __restrict__ hyper,
                                             const u16* __restrict__ h_bf,
                                             float* __restrict__ part){
  __shared__ u32 lds[32*65 + 32*33];      // 12.5KB; bbin cursors alias first 293 ints
  int bid = blockIdx.x, tid = threadIdx.x;
  if (bid < NB_H){
    int* cur = (int*)lds;
    for (int i = tid; i < NBKT; i += 256)
      cur[i] = bbase[i] + cnt_bb[i*NB_H + bid];
    __syncthreads();
    #pragma unroll
    for (int it = 0; it < 8; ++it){
      int e4 = bid*EPB + it*1024 + tid*4;
      if (e4 < NNZ){
        int4 r4 = *(const int4*)(rows_ + e4);
        int4 c4 = *(const int4*)(cols_ + e4);
        float4 v4 = *(const float4*)(vals_ + e4);
        int rr[4] = {r4.x, r4.y, r4.z, r4.w};
        int cc[4] = {c4.x, c4.y, c4.z, c4.w};
        float vv[4] = {v4.x, v4.y, v4.z, v4.w};
        #pragma unroll
        for (int j = 0; j < 4; ++j){
          int r = min(max(rr[j],0), N_NODES-1);
          int c = min(max(cc[j],0), N_NODES-1);
          int pos = atomicAdd(&cur[r >> BSHIFT], 1);
          pos = min(max(pos,0), NNZ-1);
          int pack = ((r & (RPB-1)) << 19) | c;   // rowlocal:10b | col:19b
          u64 pk = (u64)(u32)pack | ((u64)(u32)__float_as_int(vv[j]) << 32);
          __builtin_nontemporal_store(pk, (u64*)&bin[pos]);
        }
      }
    }
    return;
  }
  step3_dispatch(bid - NB_H, hyper, h_bf, part, lds);
}

// Finalize: per bucket, LDS row-histogram -> LDS scan -> write rowptr ->
// LDS-cursor scatter of {col,val} into the bucket's L2-resident output range.
__global__ __launch_bounds__(256) void k_bfin(const int2* __restrict__ bin,
                                              const int* __restrict__ bbase,
                                              int* __restrict__ rowptr,
                                              int2* __restrict__ pair_s){
  __shared__ int s_hist[RPB];
  __shared__ int sA[RPB], sB[RPB];
  int b = blockIdx.x, tid = threadIdx.x;
  int ebeg = bbase[b], eend = bbase[b+1];
  int base = ebeg;
  for (int i = tid; i < RPB; i += 256) s_hist[i] = 0;
  __syncthreads();
  for (int e = ebeg + tid; e < eend; e += 256){
    int pack = bin[e].x;
    atomicAdd(&s_hist[(pack >> 19) & (RPB-1)], 1);
  }
  __syncthreads();
  for (int i = tid; i < RPB; i += 256) sA[i] = s_hist[i];
  __syncthreads();
  int* cur = sA; int* nxt = sB;
  for (int off = 1; off < RPB; off <<= 1){
    for (int i = tid; i < RPB; i += 256)
      nxt[i] = cur[i] + ((i >= off) ? cur[i-off] : 0);
    __syncthreads();
    int* t = cur; cur = nxt; nxt = t;
  }
  // cur = inclusive; cursor/rowptr value = base + (inclusive - hist) = exclusive
  int r0 = b << BSHIFT;
  for (int i = tid; i < RPB; i += 256){
    int v = base + cur[i] - s_hist[i];
    nxt[i] = v;                          // nxt reused as the scatter cursor
    if (r0 + i <= N_NODES) rowptr[r0 + i] = v;
  }
  __syncthreads();
  for (int e = ebeg + tid; e < eend; e += 256){
    int2 pv = bin[e];
    int rl = (pv.x >> 19) & (RPB-1);
    int c  = pv.x & 0x7FFFF;
    int pos = atomicAdd(&nxt[rl], 1);
    pos = min(max(pos,0), NNZ-1);
    pair_s[pos] = make_int2(c, pv.y);
  }
}

// ---------------- spmm (+merged partial-tile reduce) --------------------------
// Blocks [0,NB_RED): full-range sum of step3 partials -> tmp (plain stores, no
// atomics, no pre-zero). Blocks [NB_RED,...): one wave per row, 8-deep gather
// pipeline. Pair stream via nontemporal loads (read-once; don't evict h from
// L2); gout via nontemporal stores (no RFO/write-allocate pollution).
__global__ __launch_bounds__(256) void k_spmm(const int* __restrict__ rp,
                                              const int2* __restrict__ ps,
                                              const u16* __restrict__ h,
                                              float* __restrict__ gout,
                                              const float* __restrict__ part,
                                              float* __restrict__ tmp){
  int bid = blockIdx.x;
  if (bid < NB_RED){
    int j = (bid & 31)*256 + threadIdx.x;
    float s = 0.f;
    if (bid < 32){
      for (int b = 0; b < NB_S3U; ++b) s += part[(size_t)b*8192 + j];
      tmp[j] = s;
    } else {
      for (int b = NB_S3U; b < NB_S3; ++b) s += part[(size_t)b*8192 + j];
      tmp[HYP*D + j] = s;
    }
    return;
  }
  int r = (bid - NB_RED)*4 + (threadIdx.x>>6);
  int lane = threadIdx.x & 63;
  int beg = rp[r], end = rp[r+1];
  float acc = 0.f;
  for (int base = beg; base < end; base += 64){
    int c = 0; float v = 0.f;
    if (base + lane < end){
      u64 pvu = __builtin_nontemporal_load((const u64*)(ps + base + lane));
      c = (int)(u32)pvu; v = __int_as_float((int)(u32)(pvu >> 32));
    }
    int n = end - base; if (n > 64) n = 64;
    for (int e = 0; e < n; e += 8){
      int ce[8]; float ve[8]; float hv[8];
      #pragma unroll
      for (int j = 0; j < 8; ++j){
        ce[j] = __shfl(c, e + j);
        ve[j] = __shfl(v, e + j);
      }
      #pragma unroll
      for (int j = 0; j < 8; ++j)
        hv[j] = bf2f(h[(size_t)ce[j]*64 + lane]);   // 8 independent gathers
      #pragma unroll
      for (int j = 0; j < 8; ++j)
        acc += ve[j] * hv[j];
    }
  }
  __builtin_nontemporal_store(acc, &gout[(size_t)r*64 + lane]);
}

extern "C" void kernel_launch(void* const* d_in, const int* in_sizes, int n_in,
                              void* d_out, int out_size, void* d_ws, size_t ws_size,
                              hipStream_t stream) {
  const float* user_emb = (const float*)d_in[0];
  const float* item_emb = (const float*)d_in[1];
  const float* user_w   = (const float*)d_in[2];
  const float* item_w   = (const float*)d_in[3];
  const float* adj_vals = (const float*)d_in[4];
  const int* adj_rows = (const int*)d_in[5];
  const int* adj_cols = (const int*)d_in[6];
  float* out = (float*)d_out;

  // ws (~117 MB): hyper 76.8M + h_bf 38.4M + rowptr 1.2M + cnt_bb 0.6M + misc
  char* w = (char*)d_ws;
  auto alloc = [&](size_t b){ void* p = (void*)w; w += (b + 255) & ~(size_t)255; return p; };
  u16*   hyper  = (u16*)  alloc((size_t)N_NODES*HYP*2);
  u16*   h_bf   = (u16*)  alloc((size_t)N_NODES*D*2);
  int*   rowptr = (int*)  alloc((size_t)(N_NODES+1)*4);
  int*   cnt_bb = (int*)  alloc((size_t)NBKT*NB_H*4);
  int*   btot   = (int*)  alloc((size_t)NBKT*4);
  int*   bbase  = (int*)  alloc((size_t)(NBKT+1)*4);
  float* tmp_u  = (float*)alloc((size_t)HYP*D*4);  // tmp_i = tmp_u + HYP*D
  float* tmp_i  = (float*)alloc((size_t)HYP*D*4);
  (void)tmp_i;

  // Overlays on out (regions free until noted launch):
  int2*  pair_s = (int2*)(out + OUT_PAIR);         // hgnn[1]: free until gemm1
  float* part   = out + OUT_PART;                  // after pair_s, same region
  int2*  bin    = (int2*)(out + OUT_BIN);          // gcn[1]: free until l1 spmm
  float* hsum   = out;                             // fp32 hidden-sum accumulator

  // 1. bucket-hist (LDS atomics) || hyper-GEMM (emb fp32 direct) || init
  k_front<<<NB_H + NB_GEMM + NB_INIT, 256, 0, stream>>>(
      user_emb, item_emb, h_bf, hsum, adj_rows, cnt_bb, user_w, item_w, hyper);

  // 2-3. scan block-bucket matrix; bucket edge offsets
  k_bscan2<<<NBKT, 256, 0, stream>>>(cnt_bb, btot);
  k_bbase<<<1, 256, 0, stream>>>(btot, bbase);

  // 4. bin edges by bucket || step3 layer 0
  k_mid<<<NB_H + NB_S3, 256, 0, stream>>>(adj_rows, adj_cols, adj_vals,
                                          cnt_bb, bbase, bin, hyper, h_bf, part);

  // 5. finalize CSR (rowptr + row-sorted pairs, L2-resident per-bucket scatter)
  k_bfin<<<NBKT, 256, 0, stream>>>(bin, bbase, rowptr, pair_s);

  // 6. layer-0 spmm || reduce(l0 partials -> tmp)
  k_spmm<<<NB_RED + NB_SPMM, 256, 0, stream>>>(rowptr, pair_s, h_bf,
                                               out + OUT_GCN0, part, tmp_u);
  // 7. layer-0 fused hg GEMM + epilogue
  k_gemm_tall<128,64,true,true><<<NB_GEMM, 256, 0, stream>>>(
      hyper, tmp_u, tmp_u + HYP*D, out + OUT_HG0, out + OUT_GCN0, hsum, h_bf, UB64);

  // 8. step3 layer 1 (h_bf updated by gemm0)
  k_step3<<<NB_S3, 256, 0, stream>>>(hyper, h_bf, part);
  // 9. layer-1 spmm || reduce
  k_spmm<<<NB_RED + NB_SPMM, 256, 0, stream>>>(rowptr, pair_s, h_bf,
                                               out + OUT_GCN0 + SZL, part, tmp_u);
  // 10. layer-1 fused hg GEMM + epilogue
  k_gemm_tall<128,64,true,true><<<NB_GEMM, 256, 0, stream>>>(
      hyper, tmp_u, tmp_u + HYP*D, out + OUT_HG0 + SZL, out + OUT_GCN0 + SZL,
      hsum, h_bf, UB64);
}

// Round 9
// 917.609 us; speedup vs baseline: 1.3573x; 1.0866x over previous
//
#include <hip/hip_runtime.h>

typedef unsigned short u16;
typedef unsigned int u32;
typedef unsigned long long u64;

#define N_USERS 100000
#define N_ITEMS 200000
#define N_NODES 300000
#define D 64
#define HYP 128
#define NNZ 4000000

// out is 96M fp32 elems: [user_out|item_out|gcn_hidden(2)|hgnn_hidden(2)]
constexpr long long SZL      = 19200000LL;        // one 300000x64 tensor
constexpr long long OUT_GCN0 = SZL;               // gcn_hidden base
constexpr long long OUT_HG0  = 3*SZL;             // hgnn_hidden base
// CSR {col,val} pairs overlaid on hgnn[l=1] region [4*SZL,5*SZL): last read by
// layer-1 spmm; hgnn[1] written only by the final fused GEMM after that.
constexpr long long OUT_PAIR = 4*SZL;
// step3 partial tiles (587 x 8192 floats = 19.2MB) after pair_s, same region.
constexpr long long OUT_PART = OUT_PAIR + 8000000LL;
// bin (bucketed edges, NNZ int2 = 32MB) overlaid on gcn_hidden[l=1] region
// [2*SZL,3*SZL): consumed by k_bfin, long before layer-1 spmm writes gcn[1].
constexpr long long OUT_BIN  = 2*SZL;

// ---- bucketed CSR build geometry ----
#define BSHIFT 10
#define RPB 1024                                   // rows per bucket
constexpr int NBKT = (N_NODES + RPB - 1)/RPB;      // 293 buckets
#define EPB 8192                                   // edges per stage-1 block
constexpr int NB_H = (NNZ + EPB - 1)/EPB;          // 489 stage-1 blocks

#define S3_CHUNK 512
constexpr int NB_S3U = (N_USERS + S3_CHUNK - 1)/S3_CHUNK;  // 196
constexpr int NB_S3I = (N_ITEMS + S3_CHUNK - 1)/S3_CHUNK;  // 391
constexpr int NB_S3  = NB_S3U + NB_S3I;                    // 587
constexpr int UB64   = N_USERS/32;                         // 3125 user gemm blocks
constexpr int NB_GEMM= N_NODES/32;                         // 9375
constexpr int NB_INIT= 9375;                               // init blocks
constexpr int NB_SPMM= N_NODES/4;                          // 75000
constexpr int NB_RED = 64;                                 // reduce blocks (32 user + 32 item)

typedef __attribute__((ext_vector_type(8))) short short8;
typedef __attribute__((ext_vector_type(4))) float f32x4;

__device__ __forceinline__ float bf2f(u16 u){ u32 i = ((u32)u) << 16; return __builtin_bit_cast(float, i); }
__device__ __forceinline__ u16 f2bf(float f){
  u32 i = __builtin_bit_cast(u32, f);
  return (u16)((i + 0x7FFFu + ((i >> 16) & 1u)) >> 16);
}

// ---------------- init body: emb (fp32) -> h_bf (bf16), hsum (fp32) ----------
__device__ __forceinline__ void init_body(int t, const float* __restrict__ ue,
                                          const float* __restrict__ ie,
                                          u16* __restrict__ h_bf, float* __restrict__ hsum){
  int base = t*8;
  const float* src = (base < N_USERS*D) ? (ue + base) : (ie + (base - N_USERS*D));
  float4 v0 = *(const float4*)(src);
  float4 v1 = *(const float4*)(src + 4);
  *(float4*)(hsum + base)     = v0;
  *(float4*)(hsum + base + 4) = v1;
  uint4 p;
  p.x = (u32)f2bf(v0.x) | ((u32)f2bf(v0.y)<<16);
  p.y = (u32)f2bf(v0.z) | ((u32)f2bf(v0.w)<<16);
  p.z = (u32)f2bf(v1.x) | ((u32)f2bf(v1.y)<<16);
  p.w = (u32)f2bf(v1.z) | ((u32)f2bf(v1.w)<<16);
  *(uint4*)(h_bf + base) = p;
}

// ---------------- GEMM body ---------------------------------------------------
// C[M x N] = A[M x K] @ B[K x N]; A row-major bf16 (AF32=false) or fp32
// converted on the fly with the same f2bf rounding (AF32=true, bit-identical).
// B fp32 staged in LDS as bf16. 32 rows/block, 4 waves. User+item merged.
// FUSE: layer epilogue h = gcn+hg; hsum += h; hbf = bf16(h); hg nontemporal.
template<int K, int N, bool C32, bool FUSE, bool AF32>
__device__ __forceinline__ void gemm_body(int bid, const void* __restrict__ A0,
                                          const float* __restrict__ Bu,
                                          const float* __restrict__ Bi,
                                          void* __restrict__ Cv,
                                          const float* __restrict__ gcn0,
                                          float* __restrict__ hsum0,
                                          u16* __restrict__ hbf0,
                                          int ublocks, u32* blds){
  bool it = bid >= ublocks;
  int blk = it ? bid - ublocks : bid;
  const float* B = it ? Bi : Bu;
  size_t aoff = it ? (size_t)ublocks*32*K : 0;
  size_t co   = it ? (size_t)ublocks*32*N : 0;

  constexpr int SROW = N + 2;                 // padded u16 stride (odd dword stride)
  constexpr int PAIRS = K*N/2;
  for (int p = threadIdx.x; p < PAIRS; p += 256){
    int k = p/(N/2), c2 = p%(N/2);
    float f0 = B[2*p], f1 = B[2*p+1];
    blds[k*(SROW/2) + c2] = (u32)f2bf(f0) | ((u32)f2bf(f1)<<16);
  }
  __syncthreads();
  const u16* bl = (const u16*)blds;
  int wave = threadIdx.x>>6, lane = threadIdx.x&63, q = lane>>4, lm = lane&15;
  constexpr int NT = N/32;
  int mt = wave>>1, ntb = (wave&1)*NT;
  int r0 = blk*32;
  f32x4 acc[NT];
  #pragma unroll
  for (int nt=0; nt<NT; ++nt) acc[nt] = (f32x4){0.f,0.f,0.f,0.f};
  size_t arow = aoff + (size_t)(r0 + mt*16 + lm)*K + q*8;
  #pragma unroll
  for (int ks = 0; ks < K/32; ++ks){
    short8 a;
    if (AF32){
      const float* af = (const float*)A0 + arow + ks*32;
      float4 f0 = *(const float4*)af;
      float4 f1 = *(const float4*)(af + 4);
      a[0]=(short)f2bf(f0.x); a[1]=(short)f2bf(f0.y);
      a[2]=(short)f2bf(f0.z); a[3]=(short)f2bf(f0.w);
      a[4]=(short)f2bf(f1.x); a[5]=(short)f2bf(f1.y);
      a[6]=(short)f2bf(f1.z); a[7]=(short)f2bf(f1.w);
    } else {
      a = *(const short8*)((const u16*)A0 + arow + ks*32);
    }
    #pragma unroll
    for (int nt = 0; nt < NT; ++nt){
      short8 b;
      #pragma unroll
      for (int j = 0; j < 8; ++j)
        b[j] = (short)bl[(ks*32 + q*8 + j)*SROW + (ntb+nt)*16 + lm];
      acc[nt] = __builtin_amdgcn_mfma_f32_16x16x32_bf16(a, b, acc[nt], 0, 0, 0);
    }
  }
  #pragma unroll
  for (int nt = 0; nt < NT; ++nt)
    #pragma unroll
    for (int r = 0; r < 4; ++r){
      int row = r0 + mt*16 + q*4 + r;       // C/D: col=lane&15, row=quad*4+reg (m89)
      int col = (ntb+nt)*16 + lm;
      size_t idx = co + (size_t)row*N + col;
      if (C32){
        float hg = acc[nt][r];
        if (FUSE){
          __builtin_nontemporal_store(hg, &((float*)Cv)[idx]);  // hg: streaming
          float hv = gcn0[idx] + hg;
          hsum0[idx] += hv;
          hbf0[idx] = f2bf(hv);
        } else {
          ((float*)Cv)[idx] = hg;
        }
      } else {
        ((u16*)Cv)[idx] = f2bf(acc[nt][r]);
      }
    }
}

template<int K, int N, bool C32, bool FUSE>
__global__ __launch_bounds__(256) void k_gemm_tall(const u16* __restrict__ A0,
                                                   const float* __restrict__ Bu,
                                                   const float* __restrict__ Bi,
                                                   void* __restrict__ Cv,
                                                   const float* __restrict__ gcn0,
                                                   float* __restrict__ hsum0,
                                                   u16* __restrict__ hbf0,
                                                   int ublocks){
  __shared__ u32 blds[K*(N+2)/2];
  gemm_body<K,N,C32,FUSE,false>((int)blockIdx.x, A0, Bu, Bi, Cv, gcn0, hsum0, hbf0, ublocks, blds);
}

// k_front: bucket-histogram (LDS atomics only) || hyper GEMM (emb fp32 direct,
// no init dependency) || init (streaming). All independent throughput work.
__global__ __launch_bounds__(256) void k_front(const float* __restrict__ ue,
                                               const float* __restrict__ ie,
                                               u16* __restrict__ h_bf,
                                               float* __restrict__ hsum,
                                               const int* __restrict__ rows_,
                                               int* __restrict__ cnt_bb,
                                               const float* __restrict__ user_w,
                                               const float* __restrict__ item_w,
                                               u16* __restrict__ hyper){
  __shared__ u32 shmem[64*(HYP+2)/2];     // 16.6KB; bucket hist aliases first 293 ints
  int bid = blockIdx.x;
  int tid = threadIdx.x;
  if (bid < NB_H){
    int* hist = (int*)shmem;
    for (int i = tid; i < NBKT; i += 256) hist[i] = 0;
    __syncthreads();
    #pragma unroll
    for (int it = 0; it < 8; ++it){
      int e4 = bid*EPB + it*1024 + tid*4;
      if (e4 < NNZ){
        int4 r4 = *(const int4*)(rows_ + e4);
        atomicAdd(&hist[min(max(r4.x,0),N_NODES-1)>>BSHIFT], 1);
        atomicAdd(&hist[min(max(r4.y,0),N_NODES-1)>>BSHIFT], 1);
        atomicAdd(&hist[min(max(r4.z,0),N_NODES-1)>>BSHIFT], 1);
        atomicAdd(&hist[min(max(r4.w,0),N_NODES-1)>>BSHIFT], 1);
      }
    }
    __syncthreads();
    for (int i = tid; i < NBKT; i += 256) cnt_bb[i*NB_H + bid] = hist[i];
    return;
  }
  if (bid < NB_H + NB_GEMM){
    int gb = bid - NB_H;
    const void* A0 = (gb < UB64) ? (const void*)ue
                                 : (const void*)(ie - (size_t)UB64*32*64);
    gemm_body<64,HYP,false,false,true>(gb, A0, user_w, item_w, hyper,
                                       nullptr, nullptr, nullptr, UB64, shmem);
    return;
  }
  init_body((bid - NB_H - NB_GEMM)*256 + tid, ue, ie, h_bf, hsum);
}

// Per-bucket exclusive scan of cnt_bb over the 489 stage-1 blocks.
__global__ __launch_bounds__(256) void k_bscan2(int* __restrict__ cnt_bb,
                                                int* __restrict__ btot){
  __shared__ int sO[512], sA[512], sB[512];
  int b = blockIdx.x, tid = threadIdx.x;
  for (int i = tid; i < 512; i += 256){
    int v = (i < NB_H) ? cnt_bb[b*NB_H + i] : 0;
    sO[i] = v; sA[i] = v;
  }
  __syncthreads();
  int* cur = sA; int* nxt = sB;
  for (int off = 1; off < 512; off <<= 1){
    for (int i = tid; i < 512; i += 256)
      nxt[i] = cur[i] + ((i >= off) ? cur[i-off] : 0);
    __syncthreads();
    int* t = cur; cur = nxt; nxt = t;
  }
  for (int i = tid; i < NB_H; i += 256)
    cnt_bb[b*NB_H + i] = cur[i] - sO[i];    // exclusive
  if (tid == 0) btot[b] = cur[NB_H-1];
}

// Exclusive scan of btot[NBKT] -> bbase[NBKT+1] (bucket edge offsets).
__global__ __launch_bounds__(256) void k_bbase(const int* __restrict__ btot,
                                               int* __restrict__ bbase){
  __shared__ int sA[512], sB[512];
  int tid = threadIdx.x;
  for (int i = tid; i < 512; i += 256) sA[i] = (i < NBKT) ? btot[i] : 0;
  __syncthreads();
  int* cur = sA; int* nxt = sB;
  for (int off = 1; off < 512; off <<= 1){
    for (int i = tid; i < 512; i += 256)
      nxt[i] = cur[i] + ((i >= off) ? cur[i-off] : 0);
    __syncthreads();
    int* t = cur; cur = nxt; nxt = t;
  }
  for (int i = tid; i <= NBKT; i += 256)
    bbase[i] = (i == 0) ? 0 : cur[i-1];
}

// ---------------- step3: partial tiles (no hot atomics) ----------------------
__device__ __forceinline__ void step3_body(const u16* __restrict__ Hy,
                                           const u16* __restrict__ Hm,
                                           float* __restrict__ outp, int rows, int k0,
                                           u32* __restrict__ lds){
  u32* hyl = lds;            // 32 k-rows x 128 elems, stride 130 u16 (65 u32)
  u32* hml = lds + 32*65;    // 32 k-rows x 64 elems,  stride 66 u16 (33 u32)
  const u16* hyl16 = (const u16*)hyl;
  const u16* hml16 = (const u16*)hml;
  int tid = threadIdx.x;
  int wave = tid>>6, lane = tid&63, q = lane>>4, lm = lane&15;
  f32x4 acc[2][4];
  #pragma unroll
  for (int i=0;i<2;i++)
    #pragma unroll
    for (int j=0;j<4;j++) acc[i][j] = (f32x4){0.f,0.f,0.f,0.f};
  for (int kk=0; kk<S3_CHUNK/32; ++kk){
    int kb = k0 + kk*32;
    #pragma unroll
    for (int d0=0; d0<8; ++d0){
      int d = d0*256 + tid;
      int kr = d>>6, c2 = d&63, g = kb+kr;
      hyl[kr*65 + c2] = (g < rows) ? ((const u32*)Hy)[(size_t)g*64 + c2] : 0u;
    }
    #pragma unroll
    for (int d0=0; d0<4; ++d0){
      int d = d0*256 + tid;
      int kr = d>>5, c2 = d&31, g = kb+kr;
      hml[kr*33 + c2] = (g < rows) ? ((const u32*)Hm)[(size_t)g*32 + c2] : 0u;
    }
    __syncthreads();
    short8 a[2], b[4];
    #pragma unroll
    for (int ml=0; ml<2; ++ml)
      #pragma unroll
      for (int j=0;j<8;j++)
        a[ml][j] = (short)hyl16[(q*8+j)*130 + (wave*2+ml)*16 + lm];  // A[m][k]=Hy[k][m]
    #pragma unroll
    for (int nt=0; nt<4; ++nt)
      #pragma unroll
      for (int j=0;j<8;j++)
        b[nt][j] = (short)hml16[(q*8+j)*66 + nt*16 + lm];            // B[k][n]=Hm[k][n]
    #pragma unroll
    for (int ml=0; ml<2; ++ml)
      #pragma unroll
      for (int nt=0; nt<4; ++nt)
        acc[ml][nt] = __builtin_amdgcn_mfma_f32_16x16x32_bf16(a[ml], b[nt], acc[ml][nt], 0,0,0);
    __syncthreads();
  }
  #pragma unroll
  for (int ml=0; ml<2; ++ml)
    #pragma unroll
    for (int nt=0; nt<4; ++nt)
      #pragma unroll
      for (int r=0;r<4;r++){
        int m = (wave*2+ml)*16 + q*4 + r;
        int n = nt*16 + lm;
        __builtin_nontemporal_store(acc[ml][nt][r], &outp[m*64 + n]);
      }
}

__device__ __forceinline__ void step3_dispatch(int bid, const u16* __restrict__ hyper,
                                               const u16* __restrict__ h,
                                               float* __restrict__ part, u32* lds){
  float* outp = part + (size_t)bid*8192;
  if (bid < NB_S3U)
    step3_body(hyper, h, outp, N_USERS, bid*S3_CHUNK, lds);
  else
    step3_body(hyper + (size_t)N_USERS*HYP, h + (size_t)N_USERS*D,
               outp, N_ITEMS, (bid - NB_S3U)*S3_CHUNK, lds);
}

__global__ __launch_bounds__(256) void k_step3(const u16* __restrict__ hyper,
                                               const u16* __restrict__ h,
                                               float* __restrict__ part){
  __shared__ u32 lds[32*65 + 32*33];
  step3_dispatch((int)blockIdx.x, hyper, h, part, lds);
}

// k_mid: bbin (LDS-cursor bucket scatter) || step3 layer 0 (MFMA).
// bin stores are PLAIN (not nontemporal): each block exclusively owns ~224B
// runs per bucket (~19KB active line set) -> L2 write-allocate merges ~8
// edges/line and writes each line back once. The nt hint here caused 4x write
// amplification (158MB for a 32MB payload, round-8 counters).
__global__ __launch_bounds__(256) void k_mid(const int* __restrict__ rows_,
                                             const int* __restrict__ cols_,
                                             const float* __restrict__ vals_,
                                             const int* __restrict__ cnt_bb,
                                             const int* __restrict__ bbase,
                                             int2* __restrict__ bin,
                                             const u16* __restrict__ hyper,
                                             const u16* __restrict__ h_bf,
                                             float* __restrict__ part){
  __shared__ u32 lds[32*65 + 32*33];      // 12.5KB; bbin cursors alias first 293 ints
  int bid = blockIdx.x, tid = threadIdx.x;
  if (bid < NB_H){
    int* cur = (int*)lds;
    for (int i = tid; i < NBKT; i += 256)
      cur[i] = bbase[i] + cnt_bb[i*NB_H + bid];
    __syncthreads();
    #pragma unroll
    for (int it = 0; it < 8; ++it){
      int e4 = bid*EPB + it*1024 + tid*4;
      if (e4 < NNZ){
        int4 r4 = *(const int4*)(rows_ + e4);
        int4 c4 = *(const int4*)(cols_ + e4);
        float4 v4 = *(const float4*)(vals_ + e4);
        int rr[4] = {r4.x, r4.y, r4.z, r4.w};
        int cc[4] = {c4.x, c4.y, c4.z, c4.w};
        float vv[4] = {v4.x, v4.y, v4.z, v4.w};
        #pragma unroll
        for (int j = 0; j < 4; ++j){
          int r = min(max(rr[j],0), N_NODES-1);
          int c = min(max(cc[j],0), N_NODES-1);
          int pos = atomicAdd(&cur[r >> BSHIFT], 1);
          pos = min(max(pos,0), NNZ-1);
          int pack = ((r & (RPB-1)) << 19) | c;   // rowlocal:10b | col:19b
          bin[pos] = make_int2(pack, __float_as_int(vv[j]));  // plain: let L2 merge
        }
      }
    }
    return;
  }
  step3_dispatch(bid - NB_H, hyper, h_bf, part, lds);
}

// Finalize: per bucket, LDS row-histogram -> LDS scan -> write rowptr ->
// LDS-cursor scatter of {col,val} into the bucket's L2-resident output range.
// bin is read-once: nontemporal loads (don't evict useful state).
__global__ __launch_bounds__(256) void k_bfin(const int2* __restrict__ bin,
                                              const int* __restrict__ bbase,
                                              int* __restrict__ rowptr,
                                              int2* __restrict__ pair_s){
  __shared__ int s_hist[RPB];
  __shared__ int sA[RPB], sB[RPB];
  int b = blockIdx.x, tid = threadIdx.x;
  int ebeg = bbase[b], eend = bbase[b+1];
  int base = ebeg;
  for (int i = tid; i < RPB; i += 256) s_hist[i] = 0;
  __syncthreads();
  for (int e = ebeg + tid; e < eend; e += 256){
    u64 pvu = __builtin_nontemporal_load((const u64*)(bin + e));
    int pack = (int)(u32)pvu;
    atomicAdd(&s_hist[(pack >> 19) & (RPB-1)], 1);
  }
  __syncthreads();
  for (int i = tid; i < RPB; i += 256) sA[i] = s_hist[i];
  __syncthreads();
  int* cur = sA; int* nxt = sB;
  for (int off = 1; off < RPB; off <<= 1){
    for (int i = tid; i < RPB; i += 256)
      nxt[i] = cur[i] + ((i >= off) ? cur[i-off] : 0);
    __syncthreads();
    int* t = cur; cur = nxt; nxt = t;
  }
  // cur = inclusive; cursor/rowptr value = base + (inclusive - hist) = exclusive
  int r0 = b << BSHIFT;
  for (int i = tid; i < RPB; i += 256){
    int v = base + cur[i] - s_hist[i];
    nxt[i] = v;                          // nxt reused as the scatter cursor
    if (r0 + i <= N_NODES) rowptr[r0 + i] = v;
  }
  __syncthreads();
  for (int e = ebeg + tid; e < eend; e += 256){
    u64 pvu = __builtin_nontemporal_load((const u64*)(bin + e));
    int pack = (int)(u32)pvu;
    int rl = (pack >> 19) & (RPB-1);
    int c  = pack & 0x7FFFF;
    int pos = atomicAdd(&nxt[rl], 1);
    pos = min(max(pos,0), NNZ-1);
    pair_s[pos] = make_int2(c, (int)(u32)(pvu >> 32));
  }
}

// ---------------- spmm (+merged partial-tile reduce) --------------------------
// Blocks [0,NB_RED): full-range sum of step3 partials -> tmp (plain stores, no
// atomics, no pre-zero). Blocks [NB_RED,...): one wave per row, 8-deep gather
// pipeline. Pair stream via nontemporal loads (read-once; don't evict h from
// L2); gout via nontemporal stores (full-line coalesced streaming).
__global__ __launch_bounds__(256) void k_spmm(const int* __restrict__ rp,
                                              const int2* __restrict__ ps,
                                              const u16* __restrict__ h,
                                              float* __restrict__ gout,
                                              const float* __restrict__ part,
                                              float* __restrict__ tmp){
  int bid = blockIdx.x;
  if (bid < NB_RED){
    int j = (bid & 31)*256 + threadIdx.x;
    float s = 0.f;
    if (bid < 32){
      for (int b = 0; b < NB_S3U; ++b) s += part[(size_t)b*8192 + j];
      tmp[j] = s;
    } else {
      for (int b = NB_S3U; b < NB_S3; ++b) s += part[(size_t)b*8192 + j];
      tmp[HYP*D + j] = s;
    }
    return;
  }
  int r = (bid - NB_RED)*4 + (threadIdx.x>>6);
  int lane = threadIdx.x & 63;
  int beg = rp[r], end = rp[r+1];
  float acc = 0.f;
  for (int base = beg; base < end; base += 64){
    int c = 0; float v = 0.f;
    if (base + lane < end){
      u64 pvu = __builtin_nontemporal_load((const u64*)(ps + base + lane));
      c = (int)(u32)pvu; v = __int_as_float((int)(u32)(pvu >> 32));
    }
    int n = end - base; if (n > 64) n = 64;
    for (int e = 0; e < n; e += 8){
      int ce[8]; float ve[8]; float hv[8];
      #pragma unroll
      for (int j = 0; j < 8; ++j){
        ce[j] = __shfl(c, e + j);
        ve[j] = __shfl(v, e + j);
      }
      #pragma unroll
      for (int j = 0; j < 8; ++j)
        hv[j] = bf2f(h[(size_t)ce[j]*64 + lane]);   // 8 independent gathers
      #pragma unroll
      for (int j = 0; j < 8; ++j)
        acc += ve[j] * hv[j];
    }
  }
  __builtin_nontemporal_store(acc, &gout[(size_t)r*64 + lane]);
}

extern "C" void kernel_launch(void* const* d_in, const int* in_sizes, int n_in,
                              void* d_out, int out_size, void* d_ws, size_t ws_size,
                              hipStream_t stream) {
  const float* user_emb = (const float*)d_in[0];
  const float* item_emb = (const float*)d_in[1];
  const float* user_w   = (const float*)d_in[2];
  const float* item_w   = (const float*)d_in[3];
  const float* adj_vals = (const float*)d_in[4];
  const int* adj_rows = (const int*)d_in[5];
  const int* adj_cols = (const int*)d_in[6];
  float* out = (float*)d_out;

  // ws (~117 MB): hyper 76.8M + h_bf 38.4M + rowptr 1.2M + cnt_bb 0.6M + misc
  char* w = (char*)d_ws;
  auto alloc = [&](size_t b){ void* p = (void*)w; w += (b + 255) & ~(size_t)255; return p; };
  u16*   hyper  = (u16*)  alloc((size_t)N_NODES*HYP*2);
  u16*   h_bf   = (u16*)  alloc((size_t)N_NODES*D*2);
  int*   rowptr = (int*)  alloc((size_t)(N_NODES+1)*4);
  int*   cnt_bb = (int*)  alloc((size_t)NBKT*NB_H*4);
  int*   btot   = (int*)  alloc((size_t)NBKT*4);
  int*   bbase  = (int*)  alloc((size_t)(NBKT+1)*4);
  float* tmp_u  = (float*)alloc((size_t)HYP*D*4);  // tmp_i = tmp_u + HYP*D
  float* tmp_i  = (float*)alloc((size_t)HYP*D*4);
  (void)tmp_i;

  // Overlays on out (regions free until noted launch):
  int2*  pair_s = (int2*)(out + OUT_PAIR);         // hgnn[1]: free until gemm1
  float* part   = out + OUT_PART;                  // after pair_s, same region
  int2*  bin    = (int2*)(out + OUT_BIN);          // gcn[1]: free until l1 spmm
  float* hsum   = out;                             // fp32 hidden-sum accumulator

  // 1. bucket-hist (LDS atomics) || hyper-GEMM (emb fp32 direct) || init
  k_front<<<NB_H + NB_GEMM + NB_INIT, 256, 0, stream>>>(
      user_emb, item_emb, h_bf, hsum, adj_rows, cnt_bb, user_w, item_w, hyper);

  // 2-3. scan block-bucket matrix; bucket edge offsets
  k_bscan2<<<NBKT, 256, 0, stream>>>(cnt_bb, btot);
  k_bbase<<<1, 256, 0, stream>>>(btot, bbase);

  // 4. bin edges by bucket || step3 layer 0
  k_mid<<<NB_H + NB_S3, 256, 0, stream>>>(adj_rows, adj_cols, adj_vals,
                                          cnt_bb, bbase, bin, hyper, h_bf, part);

  // 5. finalize CSR (rowptr + row-sorted pairs, L2-resident per-bucket scatter)
  k_bfin<<<NBKT, 256, 0, stream>>>(bin, bbase, rowptr, pair_s);

  // 6. layer-0 spmm || reduce(l0 partials -> tmp)
  k_spmm<<<NB_RED + NB_SPMM, 256, 0, stream>>>(rowptr, pair_s, h_bf,
                                               out + OUT_GCN0, part, tmp_u);
  // 7. layer-0 fused hg GEMM + epilogue
  k_gemm_tall<128,64,true,true><<<NB_GEMM, 256, 0, stream>>>(
      hyper, tmp_u, tmp_u + HYP*D, out + OUT_HG0, out + OUT_GCN0, hsum, h_bf, UB64);

  // 8. step3 layer 1 (h_bf updated by gemm0)
  k_step3<<<NB_S3, 256, 0, stream>>>(hyper, h_bf, part);
  // 9. layer-1 spmm || reduce
  k_spmm<<<NB_RED + NB_SPMM, 256, 0, stream>>>(rowptr, pair_s, h_bf,
                                               out + OUT_GCN0 + SZL, part, tmp_u);
  // 10. layer-1 fused hg GEMM + epilogue
  k_gemm_tall<128,64,true,true><<<NB_GEMM, 256, 0, stream>>>(
      hyper, tmp_u, tmp_u + HYP*D, out + OUT_HG0 + SZL, out + OUT_GCN0 + SZL,
      hsum, h_bf, UB64);
}

// Round 10
// 878.958 us; speedup vs baseline: 1.4170x; 1.0440x over previous
//
#include <hip/hip_runtime.h>

typedef unsigned short u16;
typedef unsigned int u32;
typedef unsigned long long u64;

#define N_USERS 100000
#define N_ITEMS 200000
#define N_NODES 300000
#define D 64
#define HYP 128
#define NNZ 4000000

// out is 96M fp32 elems: [user_out|item_out|gcn_hidden(2)|hgnn_hidden(2)]
constexpr long long SZL      = 19200000LL;        // one 300000x64 tensor
constexpr long long OUT_GCN0 = SZL;               // gcn_hidden base
constexpr long long OUT_HG0  = 3*SZL;             // hgnn_hidden base
// CSR {col,val} pairs overlaid on hgnn[l=1] region [4*SZL,5*SZL): last read by
// layer-1 spmm; hgnn[1] written only by the final fused GEMM after that.
constexpr long long OUT_PAIR = 4*SZL;
// step3 partial tiles (587 x 8192 floats = 19.2MB) after pair_s, same region.
constexpr long long OUT_PART = OUT_PAIR + 8000000LL;
// bin (bucketed edges, NNZ int2 = 32MB) overlaid on gcn_hidden[l=1] region
// [2*SZL,3*SZL): consumed by k_bfin, long before layer-1 spmm writes gcn[1].
constexpr long long OUT_BIN  = 2*SZL;

// ---- bucketed CSR build geometry ----
#define BSHIFT 10
#define RPB 1024                                   // rows per bucket
constexpr int NBKT = (N_NODES + RPB - 1)/RPB;      // 293 buckets
#define EPB 8192                                   // edges per stage-1 block
constexpr int NB_H = (NNZ + EPB - 1)/EPB;          // 489 stage-1 blocks

#define S3_CHUNK 512
constexpr int NB_S3U = (N_USERS + S3_CHUNK - 1)/S3_CHUNK;  // 196
constexpr int NB_S3I = (N_ITEMS + S3_CHUNK - 1)/S3_CHUNK;  // 391
constexpr int NB_S3  = NB_S3U + NB_S3I;                    // 587
constexpr int UB64   = N_USERS/32;                         // 3125 user gemm blocks
constexpr int NB_GEMM= N_NODES/32;                         // 9375
constexpr int NB_INIT= 9375;                               // init blocks
constexpr int NB_SPMM= N_NODES/4;                          // 75000
constexpr int NB_RED = 64;                                 // reduce blocks (32 user + 32 item)

typedef __attribute__((ext_vector_type(8))) short short8;
typedef __attribute__((ext_vector_type(4))) float f32x4;

__device__ __forceinline__ float bf2f(u16 u){ u32 i = ((u32)u) << 16; return __builtin_bit_cast(float, i); }
__device__ __forceinline__ u16 f2bf(float f){
  u32 i = __builtin_bit_cast(u32, f);
  return (u16)((i + 0x7FFFu + ((i >> 16) & 1u)) >> 16);
}

// ---------------- init body: emb (fp32) -> h_bf (bf16), hsum (fp32) ----------
__device__ __forceinline__ void init_body(int t, const float* __restrict__ ue,
                                          const float* __restrict__ ie,
                                          u16* __restrict__ h_bf, float* __restrict__ hsum){
  int base = t*8;
  const float* src = (base < N_USERS*D) ? (ue + base) : (ie + (base - N_USERS*D));
  float4 v0 = *(const float4*)(src);
  float4 v1 = *(const float4*)(src + 4);
  *(float4*)(hsum + base)     = v0;
  *(float4*)(hsum + base + 4) = v1;
  uint4 p;
  p.x = (u32)f2bf(v0.x) | ((u32)f2bf(v0.y)<<16);
  p.y = (u32)f2bf(v0.z) | ((u32)f2bf(v0.w)<<16);
  p.z = (u32)f2bf(v1.x) | ((u32)f2bf(v1.y)<<16);
  p.w = (u32)f2bf(v1.z) | ((u32)f2bf(v1.w)<<16);
  *(uint4*)(h_bf + base) = p;
}

// ---------------- GEMM body ---------------------------------------------------
// C[M x N] = A[M x K] @ B[K x N]; A row-major bf16 (AF32=false) or fp32
// converted on the fly with the same f2bf rounding (AF32=true, bit-identical).
// B fp32 staged in LDS as bf16. 32 rows/block, 4 waves. User+item merged.
// FUSE: layer epilogue h = gcn+hg; hsum += h; hbf = bf16(h); hg nontemporal.
template<int K, int N, bool C32, bool FUSE, bool AF32>
__device__ __forceinline__ void gemm_body(int bid, const void* __restrict__ A0,
                                          const float* __restrict__ Bu,
                                          const float* __restrict__ Bi,
                                          void* __restrict__ Cv,
                                          const float* __restrict__ gcn0,
                                          float* __restrict__ hsum0,
                                          u16* __restrict__ hbf0,
                                          int ublocks, u32* blds){
  bool it = bid >= ublocks;
  int blk = it ? bid - ublocks : bid;
  const float* B = it ? Bi : Bu;
  size_t aoff = it ? (size_t)ublocks*32*K : 0;
  size_t co   = it ? (size_t)ublocks*32*N : 0;

  constexpr int SROW = N + 2;                 // padded u16 stride (odd dword stride)
  constexpr int PAIRS = K*N/2;
  for (int p = threadIdx.x; p < PAIRS; p += 256){
    int k = p/(N/2), c2 = p%(N/2);
    float f0 = B[2*p], f1 = B[2*p+1];
    blds[k*(SROW/2) + c2] = (u32)f2bf(f0) | ((u32)f2bf(f1)<<16);
  }
  __syncthreads();
  const u16* bl = (const u16*)blds;
  int wave = threadIdx.x>>6, lane = threadIdx.x&63, q = lane>>4, lm = lane&15;
  constexpr int NT = N/32;
  int mt = wave>>1, ntb = (wave&1)*NT;
  int r0 = blk*32;
  f32x4 acc[NT];
  #pragma unroll
  for (int nt=0; nt<NT; ++nt) acc[nt] = (f32x4){0.f,0.f,0.f,0.f};
  size_t arow = aoff + (size_t)(r0 + mt*16 + lm)*K + q*8;
  #pragma unroll
  for (int ks = 0; ks < K/32; ++ks){
    short8 a;
    if (AF32){
      const float* af = (const float*)A0 + arow + ks*32;
      float4 f0 = *(const float4*)af;
      float4 f1 = *(const float4*)(af + 4);
      a[0]=(short)f2bf(f0.x); a[1]=(short)f2bf(f0.y);
      a[2]=(short)f2bf(f0.z); a[3]=(short)f2bf(f0.w);
      a[4]=(short)f2bf(f1.x); a[5]=(short)f2bf(f1.y);
      a[6]=(short)f2bf(f1.z); a[7]=(short)f2bf(f1.w);
    } else {
      a = *(const short8*)((const u16*)A0 + arow + ks*32);
    }
    #pragma unroll
    for (int nt = 0; nt < NT; ++nt){
      short8 b;
      #pragma unroll
      for (int j = 0; j < 8; ++j)
        b[j] = (short)bl[(ks*32 + q*8 + j)*SROW + (ntb+nt)*16 + lm];
      acc[nt] = __builtin_amdgcn_mfma_f32_16x16x32_bf16(a, b, acc[nt], 0, 0, 0);
    }
  }
  #pragma unroll
  for (int nt = 0; nt < NT; ++nt)
    #pragma unroll
    for (int r = 0; r < 4; ++r){
      int row = r0 + mt*16 + q*4 + r;       // C/D: col=lane&15, row=quad*4+reg (m89)
      int col = (ntb+nt)*16 + lm;
      size_t idx = co + (size_t)row*N + col;
      if (C32){
        float hg = acc[nt][r];
        if (FUSE){
          __builtin_nontemporal_store(hg, &((float*)Cv)[idx]);  // hg: streaming
          float hv = gcn0[idx] + hg;
          hsum0[idx] += hv;
          hbf0[idx] = f2bf(hv);
        } else {
          ((float*)Cv)[idx] = hg;
        }
      } else {
        ((u16*)Cv)[idx] = f2bf(acc[nt][r]);
      }
    }
}

template<int K, int N, bool C32, bool FUSE>
__global__ __launch_bounds__(256) void k_gemm_tall(const u16* __restrict__ A0,
                                                   const float* __restrict__ Bu,
                                                   const float* __restrict__ Bi,
                                                   void* __restrict__ Cv,
                                                   const float* __restrict__ gcn0,
                                                   float* __restrict__ hsum0,
                                                   u16* __restrict__ hbf0,
                                                   int ublocks){
  __shared__ u32 blds[K*(N+2)/2];
  gemm_body<K,N,C32,FUSE,false>((int)blockIdx.x, A0, Bu, Bi, Cv, gcn0, hsum0, hbf0, ublocks, blds);
}

// k_front: bucket-histogram (LDS atomics only) || hyper GEMM (emb fp32 direct,
// no init dependency) || init (streaming). All independent throughput work.
__global__ __launch_bounds__(256) void k_front(const float* __restrict__ ue,
                                               const float* __restrict__ ie,
                                               u16* __restrict__ h_bf,
                                               float* __restrict__ hsum,
                                               const int* __restrict__ rows_,
                                               int* __restrict__ cnt_bb,
                                               const float* __restrict__ user_w,
                                               const float* __restrict__ item_w,
                                               u16* __restrict__ hyper){
  __shared__ u32 shmem[64*(HYP+2)/2];     // 16.6KB; bucket hist aliases first 293 ints
  int bid = blockIdx.x;
  int tid = threadIdx.x;
  if (bid < NB_H){
    int* hist = (int*)shmem;
    for (int i = tid; i < NBKT; i += 256) hist[i] = 0;
    __syncthreads();
    #pragma unroll
    for (int it = 0; it < 8; ++it){
      int e4 = bid*EPB + it*1024 + tid*4;
      if (e4 < NNZ){
        int4 r4 = *(const int4*)(rows_ + e4);
        atomicAdd(&hist[min(max(r4.x,0),N_NODES-1)>>BSHIFT], 1);
        atomicAdd(&hist[min(max(r4.y,0),N_NODES-1)>>BSHIFT], 1);
        atomicAdd(&hist[min(max(r4.z,0),N_NODES-1)>>BSHIFT], 1);
        atomicAdd(&hist[min(max(r4.w,0),N_NODES-1)>>BSHIFT], 1);
      }
    }
    __syncthreads();
    for (int i = tid; i < NBKT; i += 256) cnt_bb[i*NB_H + bid] = hist[i];
    return;
  }
  if (bid < NB_H + NB_GEMM){
    int gb = bid - NB_H;
    const void* A0 = (gb < UB64) ? (const void*)ue
                                 : (const void*)(ie - (size_t)UB64*32*64);
    gemm_body<64,HYP,false,false,true>(gb, A0, user_w, item_w, hyper,
                                       nullptr, nullptr, nullptr, UB64, shmem);
    return;
  }
  init_body((bid - NB_H - NB_GEMM)*256 + tid, ue, ie, h_bf, hsum);
}

// Per-bucket exclusive scan of cnt_bb over the 489 stage-1 blocks.
__global__ __launch_bounds__(256) void k_bscan2(int* __restrict__ cnt_bb,
                                                int* __restrict__ btot){
  __shared__ int sO[512], sA[512], sB[512];
  int b = blockIdx.x, tid = threadIdx.x;
  for (int i = tid; i < 512; i += 256){
    int v = (i < NB_H) ? cnt_bb[b*NB_H + i] : 0;
    sO[i] = v; sA[i] = v;
  }
  __syncthreads();
  int* cur = sA; int* nxt = sB;
  for (int off = 1; off < 512; off <<= 1){
    for (int i = tid; i < 512; i += 256)
      nxt[i] = cur[i] + ((i >= off) ? cur[i-off] : 0);
    __syncthreads();
    int* t = cur; cur = nxt; nxt = t;
  }
  for (int i = tid; i < NB_H; i += 256)
    cnt_bb[b*NB_H + i] = cur[i] - sO[i];    // exclusive
  if (tid == 0) btot[b] = cur[NB_H-1];
}

// Exclusive scan of btot[NBKT] -> bbase[NBKT+1] (bucket edge offsets).
__global__ __launch_bounds__(256) void k_bbase(const int* __restrict__ btot,
                                               int* __restrict__ bbase){
  __shared__ int sA[512], sB[512];
  int tid = threadIdx.x;
  for (int i = tid; i < 512; i += 256) sA[i] = (i < NBKT) ? btot[i] : 0;
  __syncthreads();
  int* cur = sA; int* nxt = sB;
  for (int off = 1; off < 512; off <<= 1){
    for (int i = tid; i < 512; i += 256)
      nxt[i] = cur[i] + ((i >= off) ? cur[i-off] : 0);
    __syncthreads();
    int* t = cur; cur = nxt; nxt = t;
  }
  for (int i = tid; i <= NBKT; i += 256)
    bbase[i] = (i == 0) ? 0 : cur[i-1];
}

// ---------------- step3: partial tiles (no hot atomics) ----------------------
__device__ __forceinline__ void step3_body(const u16* __restrict__ Hy,
                                           const u16* __restrict__ Hm,
                                           float* __restrict__ outp, int rows, int k0,
                                           u32* __restrict__ lds){
  u32* hyl = lds;            // 32 k-rows x 128 elems, stride 130 u16 (65 u32)
  u32* hml = lds + 32*65;    // 32 k-rows x 64 elems,  stride 66 u16 (33 u32)
  const u16* hyl16 = (const u16*)hyl;
  const u16* hml16 = (const u16*)hml;
  int tid = threadIdx.x;
  int wave = tid>>6, lane = tid&63, q = lane>>4, lm = lane&15;
  f32x4 acc[2][4];
  #pragma unroll
  for (int i=0;i<2;i++)
    #pragma unroll
    for (int j=0;j<4;j++) acc[i][j] = (f32x4){0.f,0.f,0.f,0.f};
  for (int kk=0; kk<S3_CHUNK/32; ++kk){
    int kb = k0 + kk*32;
    #pragma unroll
    for (int d0=0; d0<8; ++d0){
      int d = d0*256 + tid;
      int kr = d>>6, c2 = d&63, g = kb+kr;
      hyl[kr*65 + c2] = (g < rows) ? ((const u32*)Hy)[(size_t)g*64 + c2] : 0u;
    }
    #pragma unroll
    for (int d0=0; d0<4; ++d0){
      int d = d0*256 + tid;
      int kr = d>>5, c2 = d&31, g = kb+kr;
      hml[kr*33 + c2] = (g < rows) ? ((const u32*)Hm)[(size_t)g*32 + c2] : 0u;
    }
    __syncthreads();
    short8 a[2], b[4];
    #pragma unroll
    for (int ml=0; ml<2; ++ml)
      #pragma unroll
      for (int j=0;j<8;j++)
        a[ml][j] = (short)hyl16[(q*8+j)*130 + (wave*2+ml)*16 + lm];  // A[m][k]=Hy[k][m]
    #pragma unroll
    for (int nt=0; nt<4; ++nt)
      #pragma unroll
      for (int j=0;j<8;j++)
        b[nt][j] = (short)hml16[(q*8+j)*66 + nt*16 + lm];            // B[k][n]=Hm[k][n]
    #pragma unroll
    for (int ml=0; ml<2; ++ml)
      #pragma unroll
      for (int nt=0; nt<4; ++nt)
        acc[ml][nt] = __builtin_amdgcn_mfma_f32_16x16x32_bf16(a[ml], b[nt], acc[ml][nt], 0,0,0);
    __syncthreads();
  }
  #pragma unroll
  for (int ml=0; ml<2; ++ml)
    #pragma unroll
    for (int nt=0; nt<4; ++nt)
      #pragma unroll
      for (int r=0;r<4;r++){
        int m = (wave*2+ml)*16 + q*4 + r;
        int n = nt*16 + lm;
        __builtin_nontemporal_store(acc[ml][nt][r], &outp[m*64 + n]);
      }
}

__device__ __forceinline__ void step3_dispatch(int bid, const u16* __restrict__ hyper,
                                               const u16* __restrict__ h,
                                               float* __restrict__ part, u32* lds){
  float* outp = part + (size_t)bid*8192;
  if (bid < NB_S3U)
    step3_body(hyper, h, outp, N_USERS, bid*S3_CHUNK, lds);
  else
    step3_body(hyper + (size_t)N_USERS*HYP, h + (size_t)N_USERS*D,
               outp, N_ITEMS, (bid - NB_S3U)*S3_CHUNK, lds);
}

__global__ __launch_bounds__(256) void k_step3(const u16* __restrict__ hyper,
                                               const u16* __restrict__ h,
                                               float* __restrict__ part){
  __shared__ u32 lds[32*65 + 32*33];
  step3_dispatch((int)blockIdx.x, hyper, h, part, lds);
}

// k_mid: bbin (LDS-cursor bucket scatter) || step3 layer 0 (MFMA).
// bin stores are PLAIN (not nontemporal): each block exclusively owns ~224B
// runs per bucket (~19KB active line set) -> L2 write-allocate merges ~8
// edges/line and writes each line back once. The nt hint here caused 4x write
// amplification (158MB for a 32MB payload, round-8 counters).
__global__ __launch_bounds__(256) void k_mid(const int* __restrict__ rows_,
                                             const int* __restrict__ cols_,
                                             const float* __restrict__ vals_,
                                             const int* __restrict__ cnt_bb,
                                             const int* __restrict__ bbase,
                                             int2* __restrict__ bin,
                                             const u16* __restrict__ hyper,
                                             const u16* __restrict__ h_bf,
                                             float* __restrict__ part){
  __shared__ u32 lds[32*65 + 32*33];      // 12.5KB; bbin cursors alias first 293 ints
  int bid = blockIdx.x, tid = threadIdx.x;
  if (bid < NB_H){
    int* cur = (int*)lds;
    for (int i = tid; i < NBKT; i += 256)
      cur[i] = bbase[i] + cnt_bb[i*NB_H + bid];
    __syncthreads();
    #pragma unroll
    for (int it = 0; it < 8; ++it){
      int e4 = bid*EPB + it*1024 + tid*4;
      if (e4 < NNZ){
        int4 r4 = *(const int4*)(rows_ + e4);
        int4 c4 = *(const int4*)(cols_ + e4);
        float4 v4 = *(const float4*)(vals_ + e4);
        int rr[4] = {r4.x, r4.y, r4.z, r4.w};
        int cc[4] = {c4.x, c4.y, c4.z, c4.w};
        float vv[4] = {v4.x, v4.y, v4.z, v4.w};
        #pragma unroll
        for (int j = 0; j < 4; ++j){
          int r = min(max(rr[j],0), N_NODES-1);
          int c = min(max(cc[j],0), N_NODES-1);
          int pos = atomicAdd(&cur[r >> BSHIFT], 1);
          pos = min(max(pos,0), NNZ-1);
          int pack = ((r & (RPB-1)) << 19) | c;   // rowlocal:10b | col:19b
          bin[pos] = make_int2(pack, __float_as_int(vv[j]));  // plain: let L2 merge
        }
      }
    }
    return;
  }
  step3_dispatch(bid - NB_H, hyper, h_bf, part, lds);
}

// Finalize: per bucket, LDS row-histogram -> LDS scan -> write rowptr ->
// LDS-cursor scatter of {col,val} into the bucket's L2-resident output range.
// bin is read-once: nontemporal loads (don't evict useful state).
__global__ __launch_bounds__(256) void k_bfin(const int2* __restrict__ bin,
                                              const int* __restrict__ bbase,
                                              int* __restrict__ rowptr,
                                              int2* __restrict__ pair_s){
  __shared__ int s_hist[RPB];
  __shared__ int sA[RPB], sB[RPB];
  int b = blockIdx.x, tid = threadIdx.x;
  int ebeg = bbase[b], eend = bbase[b+1];
  int base = ebeg;
  for (int i = tid; i < RPB; i += 256) s_hist[i] = 0;
  __syncthreads();
  for (int e = ebeg + tid; e < eend; e += 256){
    u64 pvu = __builtin_nontemporal_load((const u64*)(bin + e));
    int pack = (int)(u32)pvu;
    atomicAdd(&s_hist[(pack >> 19) & (RPB-1)], 1);
  }
  __syncthreads();
  for (int i = tid; i < RPB; i += 256) sA[i] = s_hist[i];
  __syncthreads();
  int* cur = sA; int* nxt = sB;
  for (int off = 1; off < RPB; off <<= 1){
    for (int i = tid; i < RPB; i += 256)
      nxt[i] = cur[i] + ((i >= off) ? cur[i-off] : 0);
    __syncthreads();
    int* t = cur; cur = nxt; nxt = t;
  }
  // cur = inclusive; cursor/rowptr value = base + (inclusive - hist) = exclusive
  int r0 = b << BSHIFT;
  for (int i = tid; i < RPB; i += 256){
    int v = base + cur[i] - s_hist[i];
    nxt[i] = v;                          // nxt reused as the scatter cursor
    if (r0 + i <= N_NODES) rowptr[r0 + i] = v;
  }
  __syncthreads();
  for (int e = ebeg + tid; e < eend; e += 256){
    u64 pvu = __builtin_nontemporal_load((const u64*)(bin + e));
    int pack = (int)(u32)pvu;
    int rl = (pack >> 19) & (RPB-1);
    int c  = pack & 0x7FFFF;
    int pos = atomicAdd(&nxt[rl], 1);
    pos = min(max(pos,0), NNZ-1);
    pair_s[pos] = make_int2(c, (int)(u32)(pvu >> 32));
  }
}

// ---------------- spmm (+merged partial-tile reduce) --------------------------
// Blocks [0,NB_RED): full-range sum of step3 partials -> tmp (plain stores, no
// atomics, no pre-zero). Blocks [NB_RED,...): one wave per row. DUAL-EDGE
// gathers: lanes 0-31 service edge e+2j, lanes 32-63 edge e+2j+1; each lane
// loads u32 (2 bf16) at h[ce]*64 + (lane&31)*2 -> 16 edges in flight per wave
// (was 8), half the VMEM instructions, same line traffic. Epilogue combines
// halves via shfl_xor(32); lanes 0-31 store float2 (256B/row, nontemporal).
// Padded lanes keep c=0,v=0 -> contribute 0.
__global__ __launch_bounds__(256) void k_spmm(const int* __restrict__ rp,
                                              const int2* __restrict__ ps,
                                              const u16* __restrict__ h,
                                              float* __restrict__ gout,
                                              const float* __restrict__ part,
                                              float* __restrict__ tmp){
  int bid = blockIdx.x;
  if (bid < NB_RED){
    int j = (bid & 31)*256 + threadIdx.x;
    float s = 0.f;
    if (bid < 32){
      for (int b = 0; b < NB_S3U; ++b) s += part[(size_t)b*8192 + j];
      tmp[j] = s;
    } else {
      for (int b = NB_S3U; b < NB_S3; ++b) s += part[(size_t)b*8192 + j];
      tmp[HYP*D + j] = s;
    }
    return;
  }
  int r = (bid - NB_RED)*4 + (threadIdx.x>>6);
  int lane = threadIdx.x & 63;
  int half = lane >> 5;          // 0: even edges, 1: odd edges
  int lp   = lane & 31;          // element-pair index within the row
  int beg = rp[r], end = rp[r+1];
  float acc0 = 0.f, acc1 = 0.f;
  for (int base = beg; base < end; base += 64){
    int c = 0; float v = 0.f;
    if (base + lane < end){
      u64 pvu = __builtin_nontemporal_load((const u64*)(ps + base + lane));
      c = (int)(u32)pvu; v = __int_as_float((int)(u32)(pvu >> 32));
    }
    int n = end - base; if (n > 64) n = 64;
    for (int e = 0; e < n; e += 16){
      int ce[8]; float ve[8]; u32 hw[8];
      #pragma unroll
      for (int j = 0; j < 8; ++j){
        ce[j] = __shfl(c, e + 2*j + half);
        ve[j] = __shfl(v, e + 2*j + half);
      }
      #pragma unroll
      for (int j = 0; j < 8; ++j)
        hw[j] = *(const u32*)(h + (size_t)ce[j]*64 + lp*2);  // 8 independent gathers, 2 edges each
      #pragma unroll
      for (int j = 0; j < 8; ++j){
        acc0 += ve[j] * bf2f((u16)(hw[j] & 0xFFFFu));
        acc1 += ve[j] * bf2f((u16)(hw[j] >> 16));
      }
    }
  }
  acc0 += __shfl_xor(acc0, 32);
  acc1 += __shfl_xor(acc1, 32);
  if (half == 0){
    u64 w = (u64)__builtin_bit_cast(u32, acc0) | ((u64)__builtin_bit_cast(u32, acc1) << 32);
    __builtin_nontemporal_store(w, (u64*)(gout + (size_t)r*64 + lp*2));
  }
}

extern "C" void kernel_launch(void* const* d_in, const int* in_sizes, int n_in,
                              void* d_out, int out_size, void* d_ws, size_t ws_size,
                              hipStream_t stream) {
  const float* user_emb = (const float*)d_in[0];
  const float* item_emb = (const float*)d_in[1];
  const float* user_w   = (const float*)d_in[2];
  const float* item_w   = (const float*)d_in[3];
  const float* adj_vals = (const float*)d_in[4];
  const int* adj_rows = (const int*)d_in[5];
  const int* adj_cols = (const int*)d_in[6];
  float* out = (float*)d_out;

  // ws (~117 MB): hyper 76.8M + h_bf 38.4M + rowptr 1.2M + cnt_bb 0.6M + misc
  char* w = (char*)d_ws;
  auto alloc = [&](size_t b){ void* p = (void*)w; w += (b + 255) & ~(size_t)255; return p; };
  u16*   hyper  = (u16*)  alloc((size_t)N_NODES*HYP*2);
  u16*   h_bf   = (u16*)  alloc((size_t)N_NODES*D*2);
  int*   rowptr = (int*)  alloc((size_t)(N_NODES+1)*4);
  int*   cnt_bb = (int*)  alloc((size_t)NBKT*NB_H*4);
  int*   btot   = (int*)  alloc((size_t)NBKT*4);
  int*   bbase  = (int*)  alloc((size_t)(NBKT+1)*4);
  float* tmp_u  = (float*)alloc((size_t)HYP*D*4);  // tmp_i = tmp_u + HYP*D
  float* tmp_i  = (float*)alloc((size_t)HYP*D*4);
  (void)tmp_i;

  // Overlays on out (regions free until noted launch):
  int2*  pair_s = (int2*)(out + OUT_PAIR);         // hgnn[1]: free until gemm1
  float* part   = out + OUT_PART;                  // after pair_s, same region
  int2*  bin    = (int2*)(out + OUT_BIN);          // gcn[1]: free until l1 spmm
  float* hsum   = out;                             // fp32 hidden-sum accumulator

  // 1. bucket-hist (LDS atomics) || hyper-GEMM (emb fp32 direct) || init
  k_front<<<NB_H + NB_GEMM + NB_INIT, 256, 0, stream>>>(
      user_emb, item_emb, h_bf, hsum, adj_rows, cnt_bb, user_w, item_w, hyper);

  // 2-3. scan block-bucket matrix; bucket edge offsets
  k_bscan2<<<NBKT, 256, 0, stream>>>(cnt_bb, btot);
  k_bbase<<<1, 256, 0, stream>>>(btot, bbase);

  // 4. bin edges by bucket || step3 layer 0
  k_mid<<<NB_H + NB_S3, 256, 0, stream>>>(adj_rows, adj_cols, adj_vals,
                                          cnt_bb, bbase, bin, hyper, h_bf, part);

  // 5. finalize CSR (rowptr + row-sorted pairs, L2-resident per-bucket scatter)
  k_bfin<<<NBKT, 256, 0, stream>>>(bin, bbase, rowptr, pair_s);

  // 6. layer-0 spmm || reduce(l0 partials -> tmp)
  k_spmm<<<NB_RED + NB_SPMM, 256, 0, stream>>>(rowptr, pair_s, h_bf,
                                               out + OUT_GCN0, part, tmp_u);
  // 7. layer-0 fused hg GEMM + epilogue
  k_gemm_tall<128,64,true,true><<<NB_GEMM, 256, 0, stream>>>(
      hyper, tmp_u, tmp_u + HYP*D, out + OUT_HG0, out + OUT_GCN0, hsum, h_bf, UB64);

  // 8. step3 layer 1 (h_bf updated by gemm0)
  k_step3<<<NB_S3, 256, 0, stream>>>(hyper, h_bf, part);
  // 9. layer-1 spmm || reduce
  k_spmm<<<NB_RED + NB_SPMM, 256, 0, stream>>>(rowptr, pair_s, h_bf,
                                               out + OUT_GCN0 + SZL, part, tmp_u);
  // 10. layer-1 fused hg GEMM + epilogue
  k_gemm_tall<128,64,true,true><<<NB_GEMM, 256, 0, stream>>>(
      hyper, tmp_u, tmp_u + HYP*D, out + OUT_HG0 + SZL, out + OUT_GCN0 + SZL,
      hsum, h_bf, UB64);
}

// Round 12
// 859.563 us; speedup vs baseline: 1.4490x; 1.0226x over previous
//
#include <hip/hip_runtime.h>

typedef unsigned short u16;
typedef unsigned int u32;
typedef unsigned long long u64;

#define N_USERS 100000
#define N_ITEMS 200000
#define N_NODES 300000
#define D 64
#define HYP 128
#define NNZ 4000000

// out is 96M fp32 elems: [user_out|item_out|gcn_hidden(2)|hgnn_hidden(2)]
constexpr long long SZL      = 19200000LL;        // one 300000x64 tensor
constexpr long long OUT_GCN0 = SZL;               // gcn_hidden base
constexpr long long OUT_HG0  = 3*SZL;             // hgnn_hidden base
// CSR {col,val} pairs overlaid on hgnn[l=1] region [4*SZL,5*SZL): last read by
// layer-1 spmm; hgnn[1] written only by the final fused GEMM after that.
constexpr long long OUT_PAIR = 4*SZL;
// step3 partial tiles (587 x 8192 floats = 19.2MB) after pair_s, same region.
constexpr long long OUT_PART = OUT_PAIR + 8000000LL;
// bin (bucketed edges, NNZ int2 = 32MB) overlaid on gcn_hidden[l=1] region
// [2*SZL,3*SZL): consumed by k_bfin, long before layer-1 spmm writes gcn[1].
constexpr long long OUT_BIN  = 2*SZL;

// ---- bucketed CSR build geometry ----
#define BSHIFT 10
#define RPB 1024                                   // rows per bucket
constexpr int NBKT = (N_NODES + RPB - 1)/RPB;      // 293 buckets
#define EPB 8192                                   // edges per stage-1 block
constexpr int NB_H = (NNZ + EPB - 1)/EPB;          // 489 stage-1 blocks

#define S3_CHUNK 512
constexpr int NB_S3U = (N_USERS + S3_CHUNK - 1)/S3_CHUNK;  // 196
constexpr int NB_S3I = (N_ITEMS + S3_CHUNK - 1)/S3_CHUNK;  // 391
constexpr int NB_S3  = NB_S3U + NB_S3I;                    // 587
constexpr int UB64   = N_USERS/32;                         // 3125 user gemm blocks
constexpr int NB_GEMM= N_NODES/32;                         // 9375
constexpr int NB_SPMM= N_NODES/4;                          // 75000
constexpr int NB_RED = 64;                                 // reduce blocks (32 user + 32 item)

typedef __attribute__((ext_vector_type(8))) short short8;
typedef __attribute__((ext_vector_type(4))) float f32x4;

__device__ __forceinline__ float bf2f(u16 u){ u32 i = ((u32)u) << 16; return __builtin_bit_cast(float, i); }
__device__ __forceinline__ u16 f2bf(float f){
  u32 i = __builtin_bit_cast(u32, f);
  return (u16)((i + 0x7FFFu + ((i >> 16) & 1u)) >> 16);
}

// ---------------- GEMM body ---------------------------------------------------
// C[M x N] = A[M x K] @ B[K x N]; A row-major bf16 (AF32=false) or fp32
// converted on the fly with the same f2bf rounding (AF32=true, bit-identical).
// B fp32 staged in LDS as bf16. 32 rows/block, 4 waves. User+item merged.
// FUSE: layer epilogue h = gcn+hg; hsum += h; hbf = bf16(h); hg nontemporal.
// WRINIT (requires AF32): the (wave&1)==0 waves also emit hsum=f32(A) and
// hbf=bf16(A) while staging A -- folds the old k_init into this GEMM (each
// (row,elem) is staged by exactly one such lane), saving a second 115MB read
// of emb.
template<int K, int N, bool C32, bool FUSE, bool AF32, bool WRINIT>
__device__ __forceinline__ void gemm_body(int bid, const void* __restrict__ A0,
                                          const float* __restrict__ Bu,
                                          const float* __restrict__ Bi,
                                          void* __restrict__ Cv,
                                          const float* __restrict__ gcn0,
                                          float* __restrict__ hsum0,
                                          u16* __restrict__ hbf0,
                                          int ublocks, u32* blds){
  bool it = bid >= ublocks;
  int blk = it ? bid - ublocks : bid;
  const float* B = it ? Bi : Bu;
  size_t aoff = it ? (size_t)ublocks*32*K : 0;
  size_t co   = it ? (size_t)ublocks*32*N : 0;

  constexpr int SROW = N + 2;                 // padded u16 stride (odd dword stride)
  constexpr int PAIRS = K*N/2;
  for (int p = threadIdx.x; p < PAIRS; p += 256){
    int k = p/(N/2), c2 = p%(N/2);
    float f0 = B[2*p], f1 = B[2*p+1];
    blds[k*(SROW/2) + c2] = (u32)f2bf(f0) | ((u32)f2bf(f1)<<16);
  }
  __syncthreads();
  const u16* bl = (const u16*)blds;
  int wave = threadIdx.x>>6, lane = threadIdx.x&63, q = lane>>4, lm = lane&15;
  constexpr int NT = N/32;
  int mt = wave>>1, ntb = (wave&1)*NT;
  int r0 = blk*32;
  f32x4 acc[NT];
  #pragma unroll
  for (int nt=0; nt<NT; ++nt) acc[nt] = (f32x4){0.f,0.f,0.f,0.f};
  size_t arow = aoff + (size_t)(r0 + mt*16 + lm)*K + q*8;
  #pragma unroll
  for (int ks = 0; ks < K/32; ++ks){
    short8 a;
    if (AF32){
      const float* af = (const float*)A0 + arow + ks*32;
      float4 f0 = *(const float4*)af;
      float4 f1 = *(const float4*)(af + 4);
      a[0]=(short)f2bf(f0.x); a[1]=(short)f2bf(f0.y);
      a[2]=(short)f2bf(f0.z); a[3]=(short)f2bf(f0.w);
      a[4]=(short)f2bf(f1.x); a[5]=(short)f2bf(f1.y);
      a[6]=(short)f2bf(f1.z); a[7]=(short)f2bf(f1.w);
      if (WRINIT && (wave & 1) == 0){
        // fold k_init: hsum = emb (fp32), h_bf = bf16(emb). Each (row,elem)
        // staged by exactly one lane of waves 0/2 (mt covers rows, q+ks elems).
        *(float4*)(hsum0 + arow + ks*32)     = f0;
        *(float4*)(hsum0 + arow + ks*32 + 4) = f1;
        *(short8*)(hbf0 + arow + ks*32)      = a;
      }
    } else {
      a = *(const short8*)((const u16*)A0 + arow + ks*32);
    }
    #pragma unroll
    for (int nt = 0; nt < NT; ++nt){
      short8 b;
      #pragma unroll
      for (int j = 0; j < 8; ++j)
        b[j] = (short)bl[(ks*32 + q*8 + j)*SROW + (ntb+nt)*16 + lm];
      acc[nt] = __builtin_amdgcn_mfma_f32_16x16x32_bf16(a, b, acc[nt], 0, 0, 0);
    }
  }
  #pragma unroll
  for (int nt = 0; nt < NT; ++nt)
    #pragma unroll
    for (int r = 0; r < 4; ++r){
      int row = r0 + mt*16 + q*4 + r;       // C/D: col=lane&15, row=quad*4+reg (m89)
      int col = (ntb+nt)*16 + lm;
      size_t idx = co + (size_t)row*N + col;
      if (C32){
        float hg = acc[nt][r];
        if (FUSE){
          __builtin_nontemporal_store(hg, &((float*)Cv)[idx]);  // hg: streaming
          float hv = gcn0[idx] + hg;
          hsum0[idx] += hv;
          hbf0[idx] = f2bf(hv);
        } else {
          ((float*)Cv)[idx] = hg;
        }
      } else {
        ((u16*)Cv)[idx] = f2bf(acc[nt][r]);
      }
    }
}

template<int K, int N, bool C32, bool FUSE>
__global__ __launch_bounds__(256) void k_gemm_tall(const u16* __restrict__ A0,
                                                   const float* __restrict__ Bu,
                                                   const float* __restrict__ Bi,
                                                   void* __restrict__ Cv,
                                                   const float* __restrict__ gcn0,
                                                   float* __restrict__ hsum0,
                                                   u16* __restrict__ hbf0,
                                                   int ublocks){
  __shared__ u32 blds[K*(N+2)/2];
  gemm_body<K,N,C32,FUSE,false,false>((int)blockIdx.x, A0, Bu, Bi, Cv, gcn0, hsum0, hbf0, ublocks, blds);
}

// k_front: bucket-histogram (LDS atomics only) || hyper GEMM (emb fp32 direct,
// WRINIT emits h_bf/hsum from the A-staging -- the old init blocks are gone).
__global__ __launch_bounds__(256) void k_front(const float* __restrict__ ue,
                                               const float* __restrict__ ie,
                                               u16* __restrict__ h_bf,
                                               float* __restrict__ hsum,
                                               const int* __restrict__ rows_,
                                               int* __restrict__ cnt_bb,
                                               const float* __restrict__ user_w,
                                               const float* __restrict__ item_w,
                                               u16* __restrict__ hyper){
  __shared__ u32 shmem[64*(HYP+2)/2];     // 16.6KB; bucket hist aliases first 293 ints
  int bid = blockIdx.x;
  int tid = threadIdx.x;
  if (bid < NB_H){
    int* hist = (int*)shmem;
    for (int i = tid; i < NBKT; i += 256) hist[i] = 0;
    __syncthreads();
    #pragma unroll
    for (int it = 0; it < 8; ++it){
      int e4 = bid*EPB + it*1024 + tid*4;
      if (e4 < NNZ){
        int4 r4 = *(const int4*)(rows_ + e4);
        atomicAdd(&hist[min(max(r4.x,0),N_NODES-1)>>BSHIFT], 1);
        atomicAdd(&hist[min(max(r4.y,0),N_NODES-1)>>BSHIFT], 1);
        atomicAdd(&hist[min(max(r4.z,0),N_NODES-1)>>BSHIFT], 1);
        atomicAdd(&hist[min(max(r4.w,0),N_NODES-1)>>BSHIFT], 1);
      }
    }
    __syncthreads();
    for (int i = tid; i < NBKT; i += 256) cnt_bb[i*NB_H + bid] = hist[i];
    return;
  }
  int gb = bid - NB_H;
  const void* A0 = (gb < UB64) ? (const void*)ue
                               : (const void*)(ie - (size_t)UB64*32*64);
  gemm_body<64,HYP,false,false,true,true>(gb, A0, user_w, item_w, hyper,
                                          nullptr, hsum, h_bf, UB64, shmem);
}

// Per-bucket exclusive scan of cnt_bb over the 489 stage-1 blocks.
__global__ __launch_bounds__(256) void k_bscan2(int* __restrict__ cnt_bb,
                                                int* __restrict__ btot){
  __shared__ int sO[512], sA[512], sB[512];
  int b = blockIdx.x, tid = threadIdx.x;
  for (int i = tid; i < 512; i += 256){
    int v = (i < NB_H) ? cnt_bb[b*NB_H + i] : 0;
    sO[i] = v; sA[i] = v;
  }
  __syncthreads();
  int* cur = sA; int* nxt = sB;
  for (int off = 1; off < 512; off <<= 1){
    for (int i = tid; i < 512; i += 256)
      nxt[i] = cur[i] + ((i >= off) ? cur[i-off] : 0);
    __syncthreads();
    int* t = cur; cur = nxt; nxt = t;
  }
  for (int i = tid; i < NB_H; i += 256)
    cnt_bb[b*NB_H + i] = cur[i] - sO[i];    // exclusive
  if (tid == 0) btot[b] = cur[NB_H-1];
}

// ---------------- step3: partial tiles (no hot atomics) ----------------------
__device__ __forceinline__ void step3_body(const u16* __restrict__ Hy,
                                           const u16* __restrict__ Hm,
                                           float* __restrict__ outp, int rows, int k0,
                                           u32* __restrict__ lds){
  u32* hyl = lds;            // 32 k-rows x 128 elems, stride 130 u16 (65 u32)
  u32* hml = lds + 32*65;    // 32 k-rows x 64 elems,  stride 66 u16 (33 u32)
  const u16* hyl16 = (const u16*)hyl;
  const u16* hml16 = (const u16*)hml;
  int tid = threadIdx.x;
  int wave = tid>>6, lane = tid&63, q = lane>>4, lm = lane&15;
  f32x4 acc[2][4];
  #pragma unroll
  for (int i=0;i<2;i++)
    #pragma unroll
    for (int j=0;j<4;j++) acc[i][j] = (f32x4){0.f,0.f,0.f,0.f};
  for (int kk=0; kk<S3_CHUNK/32; ++kk){
    int kb = k0 + kk*32;
    #pragma unroll
    for (int d0=0; d0<8; ++d0){
      int d = d0*256 + tid;
      int kr = d>>6, c2 = d&63, g = kb+kr;
      hyl[kr*65 + c2] = (g < rows) ? ((const u32*)Hy)[(size_t)g*64 + c2] : 0u;
    }
    #pragma unroll
    for (int d0=0; d0<4; ++d0){
      int d = d0*256 + tid;
      int kr = d>>5, c2 = d&31, g = kb+kr;
      hml[kr*33 + c2] = (g < rows) ? ((const u32*)Hm)[(size_t)g*32 + c2] : 0u;
    }
    __syncthreads();
    short8 a[2], b[4];
    #pragma unroll
    for (int ml=0; ml<2; ++ml)
      #pragma unroll
      for (int j=0;j<8;j++)
        a[ml][j] = (short)hyl16[(q*8+j)*130 + (wave*2+ml)*16 + lm];  // A[m][k]=Hy[k][m]
    #pragma unroll
    for (int nt=0; nt<4; ++nt)
      #pragma unroll
      for (int j=0;j<8;j++)
        b[nt][j] = (short)hml16[(q*8+j)*66 + nt*16 + lm];            // B[k][n]=Hm[k][n]
    #pragma unroll
    for (int ml=0; ml<2; ++ml)
      #pragma unroll
      for (int nt=0; nt<4; ++nt)
        acc[ml][nt] = __builtin_amdgcn_mfma_f32_16x16x32_bf16(a[ml], b[nt], acc[ml][nt], 0,0,0);
    __syncthreads();
  }
  #pragma unroll
  for (int ml=0; ml<2; ++ml)
    #pragma unroll
    for (int nt=0; nt<4; ++nt)
      #pragma unroll
      for (int r=0;r<4;r++){
        int m = (wave*2+ml)*16 + q*4 + r;
        int n = nt*16 + lm;
        __builtin_nontemporal_store(acc[ml][nt][r], &outp[m*64 + n]);
      }
}

__device__ __forceinline__ void step3_dispatch(int bid, const u16* __restrict__ hyper,
                                               const u16* __restrict__ h,
                                               float* __restrict__ part, u32* lds){
  float* outp = part + (size_t)bid*8192;
  if (bid < NB_S3U)
    step3_body(hyper, h, outp, N_USERS, bid*S3_CHUNK, lds);
  else
    step3_body(hyper + (size_t)N_USERS*HYP, h + (size_t)N_USERS*D,
               outp, N_ITEMS, (bid - NB_S3U)*S3_CHUNK, lds);
}

__global__ __launch_bounds__(256) void k_step3(const u16* __restrict__ hyper,
                                               const u16* __restrict__ h,
                                               float* __restrict__ part){
  __shared__ u32 lds[32*65 + 32*33];
  step3_dispatch((int)blockIdx.x, hyper, h, part, lds);
}

// k_mid: bbin (LDS-cursor bucket scatter) || step3 layer 0 (MFMA).
// bin stores are PLAIN: each block exclusively owns ~224B runs per bucket ->
// L2 write-allocate merges ~8 edges/line (nt here caused 4x amplification, r8).
// Bucket offsets re-derived from btot via a 512-wide LDS scan (k_bbase folded).
__global__ __launch_bounds__(256) void k_mid(const int* __restrict__ rows_,
                                             const int* __restrict__ cols_,
                                             const float* __restrict__ vals_,
                                             const int* __restrict__ cnt_bb,
                                             const int* __restrict__ btot,
                                             int2* __restrict__ bin,
                                             const u16* __restrict__ hyper,
                                             const u16* __restrict__ h_bf,
                                             float* __restrict__ part){
  __shared__ u32 lds[32*65 + 32*33];      // 12.5KB; bbin state aliases the front
  int bid = blockIdx.x, tid = threadIdx.x;
  if (bid < NB_H){
    int* cur = (int*)lds;                 // [0,293): cursors
    int* scA = (int*)lds + 512;           // [512,1024): scan buf A
    int* scB = (int*)lds + 1024;          // [1024,1536): scan buf B
    for (int i = tid; i < 512; i += 256) scA[i] = (i < NBKT) ? btot[i] : 0;
    __syncthreads();
    int* c = scA; int* n = scB;
    for (int off = 1; off < 512; off <<= 1){
      for (int i = tid; i < 512; i += 256)
        n[i] = c[i] + ((i >= off) ? c[i-off] : 0);
      __syncthreads();
      int* t = c; c = n; n = t;
    }
    for (int i = tid; i < NBKT; i += 256)
      cur[i] = ((i == 0) ? 0 : c[i-1]) + cnt_bb[i*NB_H + bid];
    __syncthreads();
    #pragma unroll
    for (int it = 0; it < 8; ++it){
      int e4 = bid*EPB + it*1024 + tid*4;
      if (e4 < NNZ){
        int4 r4 = *(const int4*)(rows_ + e4);
        int4 c4 = *(const int4*)(cols_ + e4);
        float4 v4 = *(const float4*)(vals_ + e4);
        int rr[4] = {r4.x, r4.y, r4.z, r4.w};
        int cc[4] = {c4.x, c4.y, c4.z, c4.w};
        float vv[4] = {v4.x, v4.y, v4.z, v4.w};
        #pragma unroll
        for (int j = 0; j < 4; ++j){
          int r = min(max(rr[j],0), N_NODES-1);
          int cl = min(max(cc[j],0), N_NODES-1);
          int pos = atomicAdd(&cur[r >> BSHIFT], 1);
          pos = min(max(pos,0), NNZ-1);
          int pack = ((r & (RPB-1)) << 19) | cl;  // rowlocal:10b | col:19b
          bin[pos] = make_int2(pack, __float_as_int(vv[j]));  // plain: let L2 merge
        }
      }
    }
    return;
  }
  step3_dispatch(bid - NB_H, hyper, h_bf, part, lds);
}

// Finalize: per bucket, LDS row-histogram -> LDS scan -> write rowptr ->
// LDS-cursor scatter of {col,val} into the bucket's L2-resident output range.
// bin is read-once: nontemporal loads. Bucket offsets from btot scan (k_bbase
// folded): ebeg = incl[b-1], eend = incl[b].
__global__ __launch_bounds__(256) void k_bfin(const int2* __restrict__ bin,
                                              const int* __restrict__ btot,
                                              int* __restrict__ rowptr,
                                              int2* __restrict__ pair_s){
  __shared__ int s_hist[RPB];
  __shared__ int sA[RPB], sB[RPB];
  int b = blockIdx.x, tid = threadIdx.x;
  // btot scan (512-wide) using sA/sB before their row-scan use
  for (int i = tid; i < 512; i += 256) sA[i] = (i < NBKT) ? btot[i] : 0;
  __syncthreads();
  int* cur = sA; int* nxt = sB;
  for (int off = 1; off < 512; off <<= 1){
    for (int i = tid; i < 512; i += 256)
      nxt[i] = cur[i] + ((i >= off) ? cur[i-off] : 0);
    __syncthreads();
    int* t = cur; cur = nxt; nxt = t;
  }
  int ebeg = (b == 0) ? 0 : cur[b-1];
  int eend = cur[b];
  int base = ebeg;
  __syncthreads();
  for (int i = tid; i < RPB; i += 256) s_hist[i] = 0;
  __syncthreads();
  for (int e = ebeg + tid; e < eend; e += 256){
    u64 pvu = __builtin_nontemporal_load((const u64*)(bin + e));
    int pack = (int)(u32)pvu;
    atomicAdd(&s_hist[(pack >> 19) & (RPB-1)], 1);
  }
  __syncthreads();
  for (int i = tid; i < RPB; i += 256) sA[i] = s_hist[i];
  __syncthreads();
  cur = sA; nxt = sB;
  for (int off = 1; off < RPB; off <<= 1){
    for (int i = tid; i < RPB; i += 256)
      nxt[i] = cur[i] + ((i >= off) ? cur[i-off] : 0);
    __syncthreads();
    int* t = cur; cur = nxt; nxt = t;
  }
  // cur = inclusive; cursor/rowptr value = base + (inclusive - hist) = exclusive
  int r0 = b << BSHIFT;
  for (int i = tid; i < RPB; i += 256){
    int v = base + cur[i] - s_hist[i];
    nxt[i] = v;                          // nxt reused as the scatter cursor
    if (r0 + i <= N_NODES) rowptr[r0 + i] = v;
  }
  __syncthreads();
  for (int e = ebeg + tid; e < eend; e += 256){
    u64 pvu = __builtin_nontemporal_load((const u64*)(bin + e));
    int pack = (int)(u32)pvu;
    int rl = (pack >> 19) & (RPB-1);
    int c  = pack & 0x7FFFF;
    int pos = atomicAdd(&nxt[rl], 1);
    pos = min(max(pos,0), NNZ-1);
    pair_s[pos] = make_int2(c, (int)(u32)(pvu >> 32));
  }
}

// ---------------- spmm (+merged partial-tile reduce) --------------------------
// Blocks [0,NB_RED): full-range sum of step3 partials -> tmp (plain stores, no
// atomics, no pre-zero). Blocks [NB_RED,...): one wave per row. DUAL-EDGE
// gathers: lanes 0-31 service edge e+2j, lanes 32-63 edge e+2j+1; each lane
// loads u32 (2 bf16) at h[ce]*64 + (lane&31)*2 -> 16 edges in flight per wave,
// half the VMEM instructions. Epilogue combines halves via shfl_xor(32);
// lanes 0-31 store float2 (256B/row, nontemporal). Padded lanes c=0,v=0 -> 0.
__global__ __launch_bounds__(256) void k_spmm(const int* __restrict__ rp,
                                              const int2* __restrict__ ps,
                                              const u16* __restrict__ h,
                                              float* __restrict__ gout,
                                              const float* __restrict__ part,
                                              float* __restrict__ tmp){
  int bid = blockIdx.x;
  if (bid < NB_RED){
    int j = (bid & 31)*256 + threadIdx.x;
    float s = 0.f;
    if (bid < 32){
      for (int b = 0; b < NB_S3U; ++b) s += part[(size_t)b*8192 + j];
      tmp[j] = s;
    } else {
      for (int b = NB_S3U; b < NB_S3; ++b) s += part[(size_t)b*8192 + j];
      tmp[HYP*D + j] = s;
    }
    return;
  }
  int r = (bid - NB_RED)*4 + (threadIdx.x>>6);
  int lane = threadIdx.x & 63;
  int half = lane >> 5;          // 0: even edges, 1: odd edges
  int lp   = lane & 31;          // element-pair index within the row
  int beg = rp[r], end = rp[r+1];
  float acc0 = 0.f, acc1 = 0.f;
  for (int base = beg; base < end; base += 64){
    int c = 0; float v = 0.f;
    if (base + lane < end){
      u64 pvu = __builtin_nontemporal_load((const u64*)(ps + base + lane));
      c = (int)(u32)pvu; v = __int_as_float((int)(u32)(pvu >> 32));
    }
    int n = end - base; if (n > 64) n = 64;
    for (int e = 0; e < n; e += 16){
      int ce[8]; float ve[8]; u32 hw[8];
      #pragma unroll
      for (int j = 0; j < 8; ++j){
        ce[j] = __shfl(c, e + 2*j + half);
        ve[j] = __shfl(v, e + 2*j + half);
      }
      #pragma unroll
      for (int j = 0; j < 8; ++j)
        hw[j] = *(const u32*)(h + (size_t)ce[j]*64 + lp*2);  // 8 gathers, 2 edges each
      #pragma unroll
      for (int j = 0; j < 8; ++j){
        acc0 += ve[j] * bf2f((u16)(hw[j] & 0xFFFFu));
        acc1 += ve[j] * bf2f((u16)(hw[j] >> 16));
      }
    }
  }
  acc0 += __shfl_xor(acc0, 32);
  acc1 += __shfl_xor(acc1, 32);
  if (half == 0){
    u64 w = (u64)__builtin_bit_cast(u32, acc0) | ((u64)__builtin_bit_cast(u32, acc1) << 32);
    __builtin_nontemporal_store(w, (u64*)(gout + (size_t)r*64 + lp*2));
  }
}

extern "C" void kernel_launch(void* const* d_in, const int* in_sizes, int n_in,
                              void* d_out, int out_size, void* d_ws, size_t ws_size,
                              hipStream_t stream) {
  const float* user_emb = (const float*)d_in[0];
  const float* item_emb = (const float*)d_in[1];
  const float* user_w   = (const float*)d_in[2];
  const float* item_w   = (const float*)d_in[3];
  const float* adj_vals = (const float*)d_in[4];
  const int* adj_rows = (const int*)d_in[5];
  const int* adj_cols = (const int*)d_in[6];
  float* out = (float*)d_out;

  // ws (~117 MB): hyper 76.8M + h_bf 38.4M + rowptr 1.2M + cnt_bb 0.6M + misc
  char* w = (char*)d_ws;
  auto alloc = [&](size_t b){ void* p = (void*)w; w += (b + 255) & ~(size_t)255; return p; };
  u16*   hyper  = (u16*)  alloc((size_t)N_NODES*HYP*2);
  u16*   h_bf   = (u16*)  alloc((size_t)N_NODES*D*2);
  int*   rowptr = (int*)  alloc((size_t)(N_NODES+1)*4);
  int*   cnt_bb = (int*)  alloc((size_t)NBKT*NB_H*4);
  int*   btot   = (int*)  alloc((size_t)NBKT*4);
  float* tmp_u  = (float*)alloc((size_t)HYP*D*4);  // tmp_i = tmp_u + HYP*D
  float* tmp_i  = (float*)alloc((size_t)HYP*D*4);
  (void)tmp_i;

  // Overlays on out (regions free until noted launch):
  int2*  pair_s = (int2*)(out + OUT_PAIR);         // hgnn[1]: free until gemm1
  float* part   = out + OUT_PART;                  // after pair_s, same region
  int2*  bin    = (int2*)(out + OUT_BIN);          // gcn[1]: free until l1 spmm
  float* hsum   = out;                             // fp32 hidden-sum accumulator

  // 1. bucket-hist (LDS atomics) || hyper-GEMM (emb fp32 direct, WRINIT emits
  //    h_bf + hsum from the A-staging; the old init pass is deleted)
  k_front<<<NB_H + NB_GEMM, 256, 0, stream>>>(
      user_emb, item_emb, h_bf, hsum, adj_rows, cnt_bb, user_w, item_w, hyper);

  // 2. scan block-bucket matrix (bucket offsets derived in consumers)
  k_bscan2<<<NBKT, 256, 0, stream>>>(cnt_bb, btot);

  // 3. bin edges by bucket || step3 layer 0
  k_mid<<<NB_H + NB_S3, 256, 0, stream>>>(adj_rows, adj_cols, adj_vals,
                                          cnt_bb, btot, bin, hyper, h_bf, part);

  // 4. finalize CSR (rowptr + row-sorted pairs, L2-resident per-bucket scatter)
  k_bfin<<<NBKT, 256, 0, stream>>>(bin, btot, rowptr, pair_s);

  // 5. layer-0 spmm || reduce(l0 partials -> tmp)
  k_spmm<<<NB_RED + NB_SPMM, 256, 0, stream>>>(rowptr, pair_s, h_bf,
                                               out + OUT_GCN0, part, tmp_u);
  // 6. layer-0 fused hg GEMM + epilogue
  k_gemm_tall<128,64,true,true><<<NB_GEMM, 256, 0, stream>>>(
      hyper, tmp_u, tmp_u + HYP*D, out + OUT_HG0, out + OUT_GCN0, hsum, h_bf, UB64);

  // 7. step3 layer 1 (h_bf updated by gemm0)
  k_step3<<<NB_S3, 256, 0, stream>>>(hyper, h_bf, part);
  // 8. layer-1 spmm || reduce
  k_spmm<<<NB_RED + NB_SPMM, 256, 0, stream>>>(rowptr, pair_s, h_bf,
                                               out + OUT_GCN0 + SZL, part, tmp_u);
  // 9. layer-1 fused hg GEMM + epilogue
  k_gemm_tall<128,64,true,true><<<NB_GEMM, 256, 0, stream>>>(
      hyper, tmp_u, tmp_u + HYP*D, out + OUT_HG0 + SZL, out + OUT_GCN0 + SZL,
      hsum, h_bf, UB64);
}